// Round 13
// baseline (257.147 us; speedup 1.0000x reference)
//
#include <hip/hip_runtime.h>
#include <hip/hip_bf16.h>
#include <math.h>

#define HH 496
#define WW 432
#define CC 64
#define BB 2
#define NN 8192
#define HW_ (HH * WW)
#define SPLIT 16
#define KVPS (NN / SPLIT)  // 512 kv per split
#define LOG2E 1.44269504088896f
#define DEFER_THR 11.541560327f  // 8 * log2(e), log2-domain defer-max threshold

#if __has_builtin(__builtin_amdgcn_exp2f)
#define EXP2(x) __builtin_amdgcn_exp2f(x)
#else
#define EXP2(x) exp2f(x)
#endif

typedef __attribute__((ext_vector_type(8))) short bhalf8;
typedef __attribute__((ext_vector_type(4))) float f32x4;

__device__ __forceinline__ unsigned short f2bf(float f) {
  union { float f; unsigned int u; } v; v.f = f;
  unsigned int r = (v.u + 0x7fffu + ((v.u >> 16) & 1u)) >> 16;
  return (unsigned short)r;
}

__device__ __forceinline__ float bf2f(unsigned short u) {
  union { unsigned int u; float f; } v;
  v.u = ((unsigned int)u) << 16;
  return v.f;
}

__device__ __forceinline__ void gload16(const void* g, void* l) {
  __builtin_amdgcn_global_load_lds(
      (const __attribute__((address_space(1))) void*)g,
      (__attribute__((address_space(3))) void*)l, 16, 0, 0);
}

// ---------------- sin/cos tables + map init ----------------
__global__ void prep_kernel(float* __restrict__ tabHS, float* __restrict__ tabHC,
                            float* __restrict__ tabWS, float* __restrict__ tabWC,
                            int* __restrict__ map) {
  int tid = blockIdx.x * blockDim.x + threadIdx.x;
  const int ntab = (HH + WW) * 32;
  if (tid < ntab) {
    int j = tid & 31;
    float theta = __expf(-(float)j * (9.210340371976184f / 32.f));
    if (tid < HH * 32) {
      int i = tid >> 5;
      float h = -1.f + 2.f * (float)i / (float)(HH - 1);
      float a = h * theta;
      tabHS[tid] = sinf(a);
      tabHC[tid] = cosf(a);
    } else {
      int t2 = tid - HH * 32;
      int i = t2 >> 5;
      float w = -1.f + 2.f * (float)i / (float)(WW - 1);
      float a = w * theta;
      tabWS[t2] = sinf(a);
      tabWC[t2] = cosf(a);
    }
  } else if (tid < ntab + BB * HW_) {
    map[tid - ntab] = -1;
  }
}

// ------ gather + RoPE + LN1 + QKV via MFMA; 32 points/block (2 blocks/CU) ---
__global__ __launch_bounds__(256) void qkv_kernel(
    const float* __restrict__ pillar, const int* __restrict__ vidx,
    const float* __restrict__ tabHS, const float* __restrict__ tabHC,
    const float* __restrict__ tabWS, const float* __restrict__ tabWC,
    const float* __restrict__ qw, const float* __restrict__ kw,
    const float* __restrict__ vw,
    const float* __restrict__ qb, const float* __restrict__ kbias,
    const float* __restrict__ vb,
    const float* __restrict__ n1g, const float* __restrict__ n1b,
    float* __restrict__ g_out, unsigned short* __restrict__ Qb,
    unsigned short* __restrict__ Kb, unsigned short* __restrict__ Vt,
    int* __restrict__ map) {
  __shared__ unsigned short Aln[32][72];
  __shared__ unsigned short Wq[64][72], Wk[64][72], Wv[64][72];
  __shared__ unsigned int Vbo[64][20];  // V bounce [c][point-pair], 16 used
  int tid = threadIdx.x, wid = tid >> 6, lane = tid & 63;
  int l16 = lane & 15, lg = lane >> 4;
  int pt0 = blockIdx.x * 32;
  int b = pt0 >> 13, n0 = pt0 & (NN - 1);

  // stage weights (bf16, rows [c][k])
  {
    int c = tid >> 2, k0 = (tid & 3) * 16;
#pragma unroll
    for (int mmm = 0; mmm < 3; mmm++) {
      const float* src = (mmm == 0 ? qw : mmm == 1 ? kw : vw) + c * 64 + k0;
      unsigned int pk[8];
#pragma unroll
      for (int j = 0; j < 8; j++) {
        float lo = src[2 * j], hi = src[2 * j + 1];
        asm("v_cvt_pk_bf16_f32 %0, %1, %2" : "=v"(pk[j]) : "v"(lo), "v"(hi));
      }
      unsigned short(*Wm)[72] = mmm == 0 ? Wq : mmm == 1 ? Wk : Wv;
      unsigned int* dst = (unsigned int*)&Wm[c][k0];
      *(uint4*)dst = make_uint4(pk[0], pk[1], pk[2], pk[3]);
      *(uint4*)(dst + 4) = make_uint4(pk[4], pk[5], pk[6], pk[7]);
    }
  }

  // phase 1: RoPE + LN1, 8 points per wave
  float n1g_l = n1g[lane], n1b_l = n1b[lane];
#pragma unroll 4
  for (int i = 0; i < 8; i++) {
    int p = wid * 8 + i;
    int pt = pt0 + p;
    float x = pillar[(size_t)pt * CC + lane];
    int pos = vidx[pt];
    int h = pos / WW, w = pos - h * WW;
    int j = lane & 31;
    float x1 = __shfl(x, j), x2 = __shfl(x, j + 32);
    float hs = tabHS[h * 32 + j], hc = tabHC[h * 32 + j];
    float ws = tabWS[w * 32 + j], wc = tabWC[w * 32 + j];
    float rope = (lane < 32) ? (x1 * hc * wc - x2 * hs * ws)
                             : (x1 * hs * ws + x2 * hc * wc);
    float gv = x + rope;
    g_out[(size_t)pt * CC + lane] = gv;
    float s = gv;
    for (int mm2 = 1; mm2 <= 32; mm2 <<= 1) s += __shfl_xor(s, mm2);
    float mean = s * (1.f / 64.f);
    float d = gv - mean;
    float vsum = d * d;
    for (int mm2 = 1; mm2 <= 32; mm2 <<= 1) vsum += __shfl_xor(vsum, mm2);
    float rstd = rsqrtf(vsum * (1.f / 64.f) + 1e-5f);
    float gn = d * rstd * n1g_l + n1b_l;
    Aln[p][lane] = f2bf(gn);
    if (lane == 0) map[b * HW_ + pos] = pt & (NN - 1);
  }
  __syncthreads();

  // phase 2: 24 MFMA jobs (2 tiles x 3 matrices x 4 ct) over 4 waves
#pragma unroll
  for (int j = 0; j < 6; j++) {
    int job = wid * 6 + j;
    int t = job / 12;
    int rem = job % 12;
    int mat = rem >> 2;
    int ct = rem & 3;
    bhalf8 aG0 = *(bhalf8*)&Aln[t * 16 + l16][lg * 8];
    bhalf8 aG1 = *(bhalf8*)&Aln[t * 16 + l16][32 + lg * 8];
    unsigned short(*Wm)[72] = mat == 0 ? Wq : mat == 1 ? Wk : Wv;
    bhalf8 bw0 = *(bhalf8*)&Wm[ct * 16 + l16][lg * 8];
    bhalf8 bw1 = *(bhalf8*)&Wm[ct * 16 + l16][32 + lg * 8];
    const float* bptr = mat == 0 ? qb : mat == 1 ? kbias : vb;
    float bias = bptr[ct * 16 + l16];
    f32x4 d = (f32x4){0.f, 0.f, 0.f, 0.f};
    d = __builtin_amdgcn_mfma_f32_16x16x32_bf16(aG0, bw0, d, 0, 0, 0);
    d = __builtin_amdgcn_mfma_f32_16x16x32_bf16(aG1, bw1, d, 0, 0, 0);
    if (mat == 0) {
#pragma unroll
      for (int r = 0; r < 4; r++) {
        size_t gi = (size_t)(pt0 + t * 16 + 4 * lg + r) * CC + ct * 16 + l16;
        Qb[gi] = f2bf((d[r] + bias) * LOG2E);  // log2-domain pre-scale
      }
    } else if (mat == 1) {
#pragma unroll
      for (int r = 0; r < 4; r++) {
        size_t gi = (size_t)(pt0 + t * 16 + 4 * lg + r) * CC + ct * 16 + l16;
        Kb[gi] = f2bf(d[r] + bias);
      }
    } else {
      float e0 = d[0] + bias, e1 = d[1] + bias;
      float e2 = d[2] + bias, e3 = d[3] + bias;
      unsigned int v0, v1;
      asm("v_cvt_pk_bf16_f32 %0, %1, %2" : "=v"(v0) : "v"(e0), "v"(e1));
      asm("v_cvt_pk_bf16_f32 %0, %1, %2" : "=v"(v1) : "v"(e2), "v"(e3));
      Vbo[ct * 16 + l16][t * 8 + 2 * lg + 0] = v0;
      Vbo[ct * 16 + l16][t * 8 + 2 * lg + 1] = v1;
    }
  }
  __syncthreads();
  // V write-out: coalesced rows of Vt[b][c][n]
  {
    int c = tid >> 2, ch = tid & 3;
    uint4 w0 = *(uint4*)&Vbo[c][ch * 4];
    *(uint4*)(Vt + ((size_t)b * CC + c) * NN + n0 + ch * 8) = w0;
  }
}

// ------- flash attention: 8 waves x 32 q (two temporal halves), SPLIT=16 ---
// Halves processed sequentially -> peak live regs ~84 -> 6 waves/SIMD;
// LDS 50KB -> 3 blocks/CU; grid 1024 fills them.
__global__ __attribute__((amdgpu_flat_work_group_size(512, 512),
                          amdgpu_waves_per_eu(6, 6))) void attn_kernel(
    const unsigned short* __restrict__ Qb, const unsigned short* __restrict__ Kb,
    const unsigned short* __restrict__ Vt,
    unsigned short* __restrict__ OPb, float* __restrict__ Mb,
    float* __restrict__ Lb) {
  __shared__ unsigned short Kt[2][64 * 64];
  __shared__ unsigned short Vl[2][64 * 64];
  __shared__ unsigned short Plds[8][16][72];  // per-wave, reused across halves
  int tidx = threadIdx.x;
  int wid = tidx >> 6, lane = tidx & 63;
  int l16 = lane & 15, lg = lane >> 4;
  int blk = blockIdx.x;
  int s = blk & (SPLIT - 1);
  int tb = blk >> 4;
  int b = tb >> 5;
  int tile = tb & 31;
  int q0 = tile * 256 + wid * 32;
  int kvbeg = s * KVPS;
  const unsigned short* Q = Qb + (size_t)b * NN * CC;
  const unsigned short* K = Kb + (size_t)b * NN * CC;
  const unsigned short* V = Vt + (size_t)b * CC * NN;

  bhalf8 bQ0 = *(const bhalf8*)(Q + (size_t)(q0 + l16) * CC + lg * 8);
  bhalf8 bQ1 = *(const bhalf8*)(Q + (size_t)(q0 + l16) * CC + 32 + lg * 8);
  bhalf8 bQ2 = *(const bhalf8*)(Q + (size_t)(q0 + 16 + l16) * CC + lg * 8);
  bhalf8 bQ3 = *(const bhalf8*)(Q + (size_t)(q0 + 16 + l16) * CC + 32 + lg * 8);

  int r8 = lane >> 3, chn = lane & 7;
  int sch = chn ^ r8;
  const unsigned short* Ksrc = K + (size_t)(8 * wid + r8) * CC + sch * 8;
  const unsigned short* Vsrc = V + (size_t)(8 * wid + r8) * NN + sch * 8;
  unsigned short* KtW = &Kt[0][0] + (8 * wid) * 64;
  unsigned short* VlW = &Vl[0][0] + (8 * wid) * 64;

  f32x4 acc0[4], acc1[4];
#pragma unroll
  for (int i = 0; i < 4; i++) {
    acc0[i] = (f32x4){0.f, 0.f, 0.f, 0.f};
    acc1[i] = (f32x4){0.f, 0.f, 0.f, 0.f};
  }
  float m0 = -1e30f, m1 = -1e30f, Lp0 = 0.f, Lp1 = 0.f;
  int sw8 = (l16 & 7) * 8;

  auto stage = [&](int bufi, int kv0) {
    gload16(Ksrc + (size_t)kv0 * CC, KtW + bufi * 4096);
    gload16(Vsrc + kv0, VlW + bufi * 4096);
  };

  // one q-half: QK^T -> softmax(log2, defer-max) -> P pack -> PV
  auto half_body = [&](const unsigned short* Kb_, const unsigned short* Vb_,
                       bhalf8 bQa, bhalf8 bQb, float& mh, float& Lph,
                       f32x4* acc) {
    f32x4 St[4];
    __builtin_amdgcn_s_setprio(1);
#pragma unroll
    for (int t = 0; t < 4; t++) {
      const unsigned short* kr = Kb_ + (16 * t + l16) * 64;
      bhalf8 aK0 = *(const bhalf8*)(kr + ((lg * 8) ^ sw8));
      bhalf8 aK1 = *(const bhalf8*)(kr + (((lg + 4) * 8) ^ sw8));
      f32x4 sa = (f32x4){0.f, 0.f, 0.f, 0.f};
      sa = __builtin_amdgcn_mfma_f32_16x16x32_bf16(aK0, bQa, sa, 0, 0, 0);
      sa = __builtin_amdgcn_mfma_f32_16x16x32_bf16(aK1, bQb, sa, 0, 0, 0);
      St[t] = sa;
    }
    __builtin_amdgcn_s_setprio(0);
    float ma = fmaxf(fmaxf(St[0][0], St[0][1]), fmaxf(St[0][2], St[0][3]));
    float mb = fmaxf(fmaxf(St[1][0], St[1][1]), fmaxf(St[1][2], St[1][3]));
    float mc = fmaxf(fmaxf(St[2][0], St[2][1]), fmaxf(St[2][2], St[2][3]));
    float md = fmaxf(fmaxf(St[3][0], St[3][1]), fmaxf(St[3][2], St[3][3]));
    float pm = fmaxf(fmaxf(ma, mb), fmaxf(mc, md));
    pm = fmaxf(pm, __shfl_xor(pm, 16));
    pm = fmaxf(pm, __shfl_xor(pm, 32));
    if (!__all(pm <= mh + DEFER_THR)) {
      float mn = fmaxf(mh, pm);
      float sc = EXP2(mh - mn);
      mh = mn;
      float scq[4];
#pragma unroll
      for (int r = 0; r < 4; r++) scq[r] = __shfl(sc, 4 * lg + r);
#pragma unroll
      for (int cg = 0; cg < 4; cg++)
#pragma unroll
        for (int r = 0; r < 4; r++) acc[cg][r] *= scq[r];
      Lph *= sc;
    }
#pragma unroll
    for (int t = 0; t < 4; t++)
#pragma unroll
      for (int r = 0; r < 4; r++) {
        float p0 = EXP2(St[t][r] - mh);
        St[t][r] = p0;
        Lph += p0;
      }
#pragma unroll
    for (int t = 0; t < 4; t++) {
      unsigned int pw0, pw1;
      float a0 = St[t][0], a1 = St[t][1], a2 = St[t][2], a3 = St[t][3];
      asm("v_cvt_pk_bf16_f32 %0, %1, %2" : "=v"(pw0) : "v"(a0), "v"(a1));
      asm("v_cvt_pk_bf16_f32 %0, %1, %2" : "=v"(pw1) : "v"(a2), "v"(a3));
      *(uint2*)&Plds[wid][l16][16 * t + 4 * lg] = make_uint2(pw0, pw1);
    }
#pragma unroll
    for (int ch = 0; ch < 2; ch++) {
      bhalf8 aP = *(bhalf8*)&Plds[wid][l16][ch * 32 + lg * 8];
      __builtin_amdgcn_s_setprio(1);
#pragma unroll
      for (int cg = 0; cg < 4; cg++) {
        bhalf8 bV = *(const bhalf8*)(Vb_ + (cg * 16 + l16) * 64 +
                                     (((4 * ch + lg) * 8) ^ sw8));
        acc[cg] = __builtin_amdgcn_mfma_f32_16x16x32_bf16(aP, bV, acc[cg], 0, 0, 0);
      }
      __builtin_amdgcn_s_setprio(0);
    }
  };

  auto body = [&](int buf, int kv0) {
    const unsigned short* Kb_ = &Kt[buf][0];
    const unsigned short* Vb_ = &Vl[buf][0];
    half_body(Kb_, Vb_, bQ0, bQ1, m0, Lp0, acc0);
    half_body(Kb_, Vb_, bQ2, bQ3, m1, Lp1, acc1);
  };

  stage(0, kvbeg);
  __syncthreads();
  const int nstep = KVPS / 64;  // 8, even
  for (int stp = 0; stp < nstep; stp += 2) {
    int kv0 = kvbeg + stp * 64;
    if (stp + 1 < nstep) stage(1, kv0 + 64);
    body(0, kv0);
    __syncthreads();
    if (stp + 2 < nstep) stage(0, kv0 + 128);
    body(1, kv0 + 64);
    __syncthreads();
  }
  size_t rowb = ((size_t)s * BB + b) * NN;
#pragma unroll
  for (int cg = 0; cg < 4; cg++)
#pragma unroll
    for (int r = 0; r < 4; r++) {
      OPb[(rowb + q0 + 4 * lg + r) * CC + cg * 16 + l16] = f2bf(acc0[cg][r]);
      OPb[(rowb + q0 + 16 + 4 * lg + r) * CC + cg * 16 + l16] = f2bf(acc1[cg][r]);
    }
  Lp0 += __shfl_xor(Lp0, 16);
  Lp0 += __shfl_xor(Lp0, 32);
  Lp1 += __shfl_xor(Lp1, 16);
  Lp1 += __shfl_xor(Lp1, 32);
  if (lg == 0) {
    Mb[rowb + q0 + l16] = m0;
    Lb[rowb + q0 + l16] = Lp0;
    Mb[rowb + q0 + 16 + l16] = m1;
    Lb[rowb + q0 + 16 + l16] = Lp1;
  }
}

// ---- combine + residual + LN2 + FFN; 32 points/block (2 blocks/CU) --------
__global__ __launch_bounds__(256) void ffn_kernel(
    const unsigned short* __restrict__ OPb, const float* __restrict__ Mb,
    const float* __restrict__ Lb, const float* __restrict__ g_in,
    const float* __restrict__ w1, const float* __restrict__ w2,
    const float* __restrict__ b1, const float* __restrict__ b2,
    const float* __restrict__ n2g, const float* __restrict__ n2b,
    float* __restrict__ upd) {
  __shared__ unsigned short Atile[32][72];
  __shared__ unsigned short Htile[32][72];
  __shared__ float aT[32][66];
  __shared__ unsigned short W1[64][72], W2[64][72];
  int tid = threadIdx.x, wid = tid >> 6, lane = tid & 63;
  int l16 = lane & 15, lg = lane >> 4;
  int pt0 = blockIdx.x * 32;

  {
    int c = tid >> 2, k0 = (tid & 3) * 16;
#pragma unroll
    for (int mmm = 0; mmm < 2; mmm++) {
      const float* src = (mmm == 0 ? w1 : w2) + c * 64 + k0;
      unsigned int pk[8];
#pragma unroll
      for (int j = 0; j < 8; j++) {
        float lo = src[2 * j], hi = src[2 * j + 1];
        asm("v_cvt_pk_bf16_f32 %0, %1, %2" : "=v"(pk[j]) : "v"(lo), "v"(hi));
      }
      unsigned short(*Wm)[72] = mmm == 0 ? W1 : W2;
      unsigned int* dst = (unsigned int*)&Wm[c][k0];
      *(uint4*)dst = make_uint4(pk[0], pk[1], pk[2], pk[3]);
      *(uint4*)(dst + 4) = make_uint4(pk[4], pk[5], pk[6], pk[7]);
    }
  }

  float n2g_l = n2g[lane], n2b_l = n2b[lane];
#pragma unroll 2
  for (int i = 0; i < 8; i++) {
    int p = wid * 8 + i;
    int pt = pt0 + p;
    float M = -1e30f;
    float mv[SPLIT];
#pragma unroll
    for (int s = 0; s < SPLIT; s++) {
      mv[s] = Mb[s * (BB * NN) + pt];
      M = fmaxf(M, mv[s]);
    }
    float accv = 0.f, Ls = 0.f;
#pragma unroll
    for (int s = 0; s < SPLIT; s++) {
      float w = EXP2(mv[s] - M);
      accv += w * bf2f(OPb[((size_t)s * (BB * NN) + pt) * CC + lane]);
      Ls += w * Lb[s * (BB * NN) + pt];
    }
    float a = accv / Ls + g_in[(size_t)pt * CC + lane];
    aT[p][lane] = a;
    float s2 = a;
    for (int mm2 = 1; mm2 <= 32; mm2 <<= 1) s2 += __shfl_xor(s2, mm2);
    float mean = s2 * (1.f / 64.f);
    float d = a - mean;
    float vsum = d * d;
    for (int mm2 = 1; mm2 <= 32; mm2 <<= 1) vsum += __shfl_xor(vsum, mm2);
    float rstd = rsqrtf(vsum * (1.f / 64.f) + 1e-5f);
    Atile[p][lane] = f2bf(d * rstd * n2g_l + n2b_l);
  }
  __syncthreads();

  // GEMM1: 8 jobs (2 tiles x 4 ct) over 4 waves
#pragma unroll
  for (int j = 0; j < 2; j++) {
    int job = wid * 2 + j;
    int t = job >> 2, ct = job & 3;
    bhalf8 aH0 = *(bhalf8*)&Atile[t * 16 + l16][lg * 8];
    bhalf8 aH1 = *(bhalf8*)&Atile[t * 16 + l16][32 + lg * 8];
    bhalf8 bw0 = *(bhalf8*)&W1[ct * 16 + l16][lg * 8];
    bhalf8 bw1 = *(bhalf8*)&W1[ct * 16 + l16][32 + lg * 8];
    float b1v = b1[ct * 16 + l16];
    f32x4 d1 = (f32x4){0.f, 0.f, 0.f, 0.f};
    d1 = __builtin_amdgcn_mfma_f32_16x16x32_bf16(aH0, bw0, d1, 0, 0, 0);
    d1 = __builtin_amdgcn_mfma_f32_16x16x32_bf16(aH1, bw1, d1, 0, 0, 0);
#pragma unroll
    for (int r = 0; r < 4; r++) {
      float h = d1[r] + b1v;
      h = 0.5f * h * (1.f + erff(h * 0.70710678118654752f));
      Htile[t * 16 + 4 * lg + r][ct * 16 + l16] = f2bf(h);
    }
  }
  __syncthreads();

  // GEMM2: 8 jobs over 4 waves
#pragma unroll
  for (int j = 0; j < 2; j++) {
    int job = wid * 2 + j;
    int t = job >> 2, ct = job & 3;
    bhalf8 aF0 = *(bhalf8*)&Htile[t * 16 + l16][lg * 8];
    bhalf8 aF1 = *(bhalf8*)&Htile[t * 16 + l16][32 + lg * 8];
    bhalf8 bw0 = *(bhalf8*)&W2[ct * 16 + l16][lg * 8];
    bhalf8 bw1 = *(bhalf8*)&W2[ct * 16 + l16][32 + lg * 8];
    float b2v = b2[ct * 16 + l16];
    f32x4 d2 = (f32x4){0.f, 0.f, 0.f, 0.f};
    d2 = __builtin_amdgcn_mfma_f32_16x16x32_bf16(aF0, bw0, d2, 0, 0, 0);
    d2 = __builtin_amdgcn_mfma_f32_16x16x32_bf16(aF1, bw1, d2, 0, 0, 0);
#pragma unroll
    for (int r = 0; r < 4; r++) {
      int p = t * 16 + 4 * lg + r;
      upd[(size_t)(pt0 + p) * CC + ct * 16 + l16] = d2[r] + b2v + aT[p][ct * 16 + l16];
    }
  }
}

// ---------------- dense output write: zeros + scattered rows, one pass -----
__global__ __launch_bounds__(256) void out_kernel(
    const int* __restrict__ map, const float* __restrict__ upd,
    float* __restrict__ out) {
  int b = blockIdx.x / (HW_ / 256);
  int pos = (blockIdx.x % (HW_ / 256)) * 256 + threadIdx.x;
  int r = map[b * HW_ + pos];
  float4 vals[16];
  if (r >= 0) {
    const float4* up = (const float4*)(upd + ((size_t)b * NN + r) * CC);
#pragma unroll
    for (int i = 0; i < 16; i++) vals[i] = up[i];
  } else {
#pragma unroll
    for (int i = 0; i < 16; i++) vals[i] = make_float4(0.f, 0.f, 0.f, 0.f);
  }
  float* o = out + (size_t)b * CC * HW_ + pos;
#pragma unroll
  for (int i = 0; i < 16; i++) {
    o[(size_t)(4 * i + 0) * HW_] = vals[i].x;
    o[(size_t)(4 * i + 1) * HW_] = vals[i].y;
    o[(size_t)(4 * i + 2) * HW_] = vals[i].z;
    o[(size_t)(4 * i + 3) * HW_] = vals[i].w;
  }
}

extern "C" void kernel_launch(void* const* d_in, const int* in_sizes, int n_in,
                              void* d_out, int out_size, void* d_ws, size_t ws_size,
                              hipStream_t stream) {
  const float* pillar = (const float*)d_in[0];
  const int* vidx = (const int*)d_in[1];
  const float* qw = (const float*)d_in[2];
  const float* qb = (const float*)d_in[3];
  const float* kw = (const float*)d_in[4];
  const float* kb = (const float*)d_in[5];
  const float* vw = (const float*)d_in[6];
  const float* vb = (const float*)d_in[7];
  const float* w1 = (const float*)d_in[8];
  const float* b1 = (const float*)d_in[9];
  const float* w2 = (const float*)d_in[10];
  const float* b2 = (const float*)d_in[11];
  const float* n1g = (const float*)d_in[12];
  const float* n1b = (const float*)d_in[13];
  const float* n2g = (const float*)d_in[14];
  const float* n2b = (const float*)d_in[15];
  float* out = (float*)d_out;

  char* ws = (char*)d_ws;
  size_t off = 0;
  auto take = [&](size_t bytes) -> char* {
    off = (off + 255) & ~(size_t)255;
    char* p = ws + off;
    off += bytes;
    return p;
  };
  float* tabHS = (float*)take((size_t)HH * 32 * 4);
  float* tabHC = (float*)take((size_t)HH * 32 * 4);
  float* tabWS = (float*)take((size_t)WW * 32 * 4);
  float* tabWC = (float*)take((size_t)WW * 32 * 4);
  float* gbuf = (float*)take((size_t)BB * NN * CC * 4);
  float* updb = (float*)take((size_t)BB * NN * CC * 4);
  unsigned short* Qb = (unsigned short*)take((size_t)BB * NN * CC * 2);
  unsigned short* Kb = (unsigned short*)take((size_t)BB * NN * CC * 2);
  unsigned short* Vt = (unsigned short*)take((size_t)BB * CC * NN * 2);
  unsigned short* OPb = (unsigned short*)take((size_t)SPLIT * BB * NN * CC * 2);
  float* Mbuf = (float*)take((size_t)SPLIT * BB * NN * 4);
  float* Lbuf = (float*)take((size_t)SPLIT * BB * NN * 4);
  int* map = (int*)take((size_t)BB * HW_ * 4);

  int preptot = (HH + WW) * 32 + BB * HW_;
  prep_kernel<<<(preptot + 255) / 256, 256, 0, stream>>>(
      tabHS, tabHC, tabWS, tabWC, map);
  qkv_kernel<<<BB * NN / 32, 256, 0, stream>>>(
      pillar, vidx, tabHS, tabHC, tabWS, tabWC, qw, kw, vw, qb, kb, vb,
      n1g, n1b, gbuf, Qb, Kb, Vt, map);
  attn_kernel<<<BB * (NN / 256) * SPLIT, 512, 0, stream>>>(Qb, Kb, Vt, OPb, Mbuf, Lbuf);
  ffn_kernel<<<BB * NN / 32, 256, 0, stream>>>(OPb, Mbuf, Lbuf, gbuf, w1, w2,
                                               b1, b2, n2g, n2b, updb);
  out_kernel<<<BB * (HW_ / 256), 256, 0, stream>>>(map, updb, out);
}

// Round 15
// 104.571 us; speedup vs baseline: 2.4591x; 2.4591x over previous
//
#include <hip/hip_runtime.h>
#include <hip/hip_bf16.h>
#include <math.h>

#define HH 496
#define WW 432
#define CC 64
#define BB 2
#define NN 8192
#define HW_ (HH * WW)
#define SPLIT 16
#define KVPS (NN / SPLIT)  // 512 kv per split
#define LOG2E 1.44269504088896f
#define DEFER_THR 11.541560327f  // 8 * log2(e), log2-domain defer-max threshold

#if __has_builtin(__builtin_amdgcn_exp2f)
#define EXP2(x) __builtin_amdgcn_exp2f(x)
#else
#define EXP2(x) exp2f(x)
#endif

typedef __attribute__((ext_vector_type(8))) short bhalf8;
typedef __attribute__((ext_vector_type(4))) float f32x4;

__device__ __forceinline__ unsigned short f2bf(float f) {
  union { float f; unsigned int u; } v; v.f = f;
  unsigned int r = (v.u + 0x7fffu + ((v.u >> 16) & 1u)) >> 16;
  return (unsigned short)r;
}

__device__ __forceinline__ float bf2f(unsigned short u) {
  union { unsigned int u; float f; } v;
  v.u = ((unsigned int)u) << 16;
  return v.f;
}

__device__ __forceinline__ void gload16(const void* g, void* l) {
  __builtin_amdgcn_global_load_lds(
      (const __attribute__((address_space(1))) void*)g,
      (__attribute__((address_space(3))) void*)l, 16, 0, 0);
}

// ---------------- sin/cos tables + map init ----------------
__global__ void prep_kernel(float* __restrict__ tabHS, float* __restrict__ tabHC,
                            float* __restrict__ tabWS, float* __restrict__ tabWC,
                            int* __restrict__ map) {
  int tid = blockIdx.x * blockDim.x + threadIdx.x;
  const int ntab = (HH + WW) * 32;
  if (tid < ntab) {
    int j = tid & 31;
    float theta = __expf(-(float)j * (9.210340371976184f / 32.f));
    if (tid < HH * 32) {
      int i = tid >> 5;
      float h = -1.f + 2.f * (float)i / (float)(HH - 1);
      float a = h * theta;
      tabHS[tid] = sinf(a);
      tabHC[tid] = cosf(a);
    } else {
      int t2 = tid - HH * 32;
      int i = t2 >> 5;
      float w = -1.f + 2.f * (float)i / (float)(WW - 1);
      float a = w * theta;
      tabWS[t2] = sinf(a);
      tabWC[t2] = cosf(a);
    }
  } else if (tid < ntab + BB * HW_) {
    map[tid - ntab] = -1;
  }
}

// ------ gather + RoPE + LN1 + QKV via MFMA; 32 points/block (2 blocks/CU) ---
__global__ __launch_bounds__(256) void qkv_kernel(
    const float* __restrict__ pillar, const int* __restrict__ vidx,
    const float* __restrict__ tabHS, const float* __restrict__ tabHC,
    const float* __restrict__ tabWS, const float* __restrict__ tabWC,
    const float* __restrict__ qw, const float* __restrict__ kw,
    const float* __restrict__ vw,
    const float* __restrict__ qb, const float* __restrict__ kbias,
    const float* __restrict__ vb,
    const float* __restrict__ n1g, const float* __restrict__ n1b,
    float* __restrict__ g_out, unsigned short* __restrict__ Qb,
    unsigned short* __restrict__ Kb, unsigned short* __restrict__ Vt,
    int* __restrict__ map) {
  __shared__ unsigned short Aln[32][72];
  __shared__ unsigned short Wq[64][72], Wk[64][72], Wv[64][72];
  __shared__ unsigned int Vbo[64][20];  // V bounce [c][point-pair], 16 used
  int tid = threadIdx.x, wid = tid >> 6, lane = tid & 63;
  int l16 = lane & 15, lg = lane >> 4;
  int pt0 = blockIdx.x * 32;
  int b = pt0 >> 13, n0 = pt0 & (NN - 1);

  // stage weights (bf16, rows [c][k])
  {
    int c = tid >> 2, k0 = (tid & 3) * 16;
#pragma unroll
    for (int mmm = 0; mmm < 3; mmm++) {
      const float* src = (mmm == 0 ? qw : mmm == 1 ? kw : vw) + c * 64 + k0;
      unsigned int pk[8];
#pragma unroll
      for (int j = 0; j < 8; j++) {
        float lo = src[2 * j], hi = src[2 * j + 1];
        asm("v_cvt_pk_bf16_f32 %0, %1, %2" : "=v"(pk[j]) : "v"(lo), "v"(hi));
      }
      unsigned short(*Wm)[72] = mmm == 0 ? Wq : mmm == 1 ? Wk : Wv;
      unsigned int* dst = (unsigned int*)&Wm[c][k0];
      *(uint4*)dst = make_uint4(pk[0], pk[1], pk[2], pk[3]);
      *(uint4*)(dst + 4) = make_uint4(pk[4], pk[5], pk[6], pk[7]);
    }
  }

  // phase 1: RoPE + LN1, 8 points per wave
  float n1g_l = n1g[lane], n1b_l = n1b[lane];
#pragma unroll 4
  for (int i = 0; i < 8; i++) {
    int p = wid * 8 + i;
    int pt = pt0 + p;
    float x = pillar[(size_t)pt * CC + lane];
    int pos = vidx[pt];
    int h = pos / WW, w = pos - h * WW;
    int j = lane & 31;
    float x1 = __shfl(x, j), x2 = __shfl(x, j + 32);
    float hs = tabHS[h * 32 + j], hc = tabHC[h * 32 + j];
    float ws = tabWS[w * 32 + j], wc = tabWC[w * 32 + j];
    float rope = (lane < 32) ? (x1 * hc * wc - x2 * hs * ws)
                             : (x1 * hs * ws + x2 * hc * wc);
    float gv = x + rope;
    g_out[(size_t)pt * CC + lane] = gv;
    float s = gv;
    for (int mm2 = 1; mm2 <= 32; mm2 <<= 1) s += __shfl_xor(s, mm2);
    float mean = s * (1.f / 64.f);
    float d = gv - mean;
    float vsum = d * d;
    for (int mm2 = 1; mm2 <= 32; mm2 <<= 1) vsum += __shfl_xor(vsum, mm2);
    float rstd = rsqrtf(vsum * (1.f / 64.f) + 1e-5f);
    float gn = d * rstd * n1g_l + n1b_l;
    Aln[p][lane] = f2bf(gn);
    if (lane == 0) map[b * HW_ + pos] = pt & (NN - 1);
  }
  __syncthreads();

  // phase 2: 24 MFMA jobs (2 tiles x 3 matrices x 4 ct) over 4 waves
#pragma unroll
  for (int j = 0; j < 6; j++) {
    int job = wid * 6 + j;
    int t = job / 12;
    int rem = job % 12;
    int mat = rem >> 2;
    int ct = rem & 3;
    bhalf8 aG0 = *(bhalf8*)&Aln[t * 16 + l16][lg * 8];
    bhalf8 aG1 = *(bhalf8*)&Aln[t * 16 + l16][32 + lg * 8];
    unsigned short(*Wm)[72] = mat == 0 ? Wq : mat == 1 ? Wk : Wv;
    bhalf8 bw0 = *(bhalf8*)&Wm[ct * 16 + l16][lg * 8];
    bhalf8 bw1 = *(bhalf8*)&Wm[ct * 16 + l16][32 + lg * 8];
    const float* bptr = mat == 0 ? qb : mat == 1 ? kbias : vb;
    float bias = bptr[ct * 16 + l16];
    f32x4 d = (f32x4){0.f, 0.f, 0.f, 0.f};
    d = __builtin_amdgcn_mfma_f32_16x16x32_bf16(aG0, bw0, d, 0, 0, 0);
    d = __builtin_amdgcn_mfma_f32_16x16x32_bf16(aG1, bw1, d, 0, 0, 0);
    if (mat == 0) {
#pragma unroll
      for (int r = 0; r < 4; r++) {
        size_t gi = (size_t)(pt0 + t * 16 + 4 * lg + r) * CC + ct * 16 + l16;
        Qb[gi] = f2bf((d[r] + bias) * LOG2E);  // log2-domain pre-scale
      }
    } else if (mat == 1) {
#pragma unroll
      for (int r = 0; r < 4; r++) {
        size_t gi = (size_t)(pt0 + t * 16 + 4 * lg + r) * CC + ct * 16 + l16;
        Kb[gi] = f2bf(d[r] + bias);
      }
    } else {
      float e0 = d[0] + bias, e1 = d[1] + bias;
      float e2 = d[2] + bias, e3 = d[3] + bias;
      unsigned int v0, v1;
      asm("v_cvt_pk_bf16_f32 %0, %1, %2" : "=v"(v0) : "v"(e0), "v"(e1));
      asm("v_cvt_pk_bf16_f32 %0, %1, %2" : "=v"(v1) : "v"(e2), "v"(e3));
      Vbo[ct * 16 + l16][t * 8 + 2 * lg + 0] = v0;
      Vbo[ct * 16 + l16][t * 8 + 2 * lg + 1] = v1;
    }
  }
  __syncthreads();
  // V write-out: coalesced rows of Vt[b][c][n]
  {
    int c = tid >> 2, ch = tid & 3;
    uint4 w0 = *(uint4*)&Vbo[c][ch * 4];
    *(uint4*)(Vt + ((size_t)b * CC + c) * NN + n0 + ch * 8) = w0;
  }
}

// ------- flash attention: R12 body, single-buffered K/V (LDS 52KB ->
// 3 blocks/CU), SPLIT=16 (grid 1024) to populate them. VGPR natural (~64).
__global__ __attribute__((amdgpu_flat_work_group_size(512, 512),
                          amdgpu_waves_per_eu(4))) void attn_kernel(
    const unsigned short* __restrict__ Qb, const unsigned short* __restrict__ Kb,
    const unsigned short* __restrict__ Vt,
    unsigned short* __restrict__ OPb, float* __restrict__ Mb,
    float* __restrict__ Lb) {
  __shared__ unsigned short Kt[64 * 64];
  __shared__ unsigned short Vl[64 * 64];
  __shared__ unsigned short Plds[8][32][72];
  int tidx = threadIdx.x;
  int wid = tidx >> 6, lane = tidx & 63;
  int l16 = lane & 15, lg = lane >> 4;
  int blk = blockIdx.x;
  int s = blk & (SPLIT - 1);
  int tb = blk >> 4;
  int b = tb >> 5;
  int tile = tb & 31;
  int q0 = tile * 256 + wid * 32;
  int kvbeg = s * KVPS;
  const unsigned short* Q = Qb + (size_t)b * NN * CC;
  const unsigned short* K = Kb + (size_t)b * NN * CC;
  const unsigned short* V = Vt + (size_t)b * CC * NN;

  bhalf8 bQ0 = *(const bhalf8*)(Q + (size_t)(q0 + l16) * CC + lg * 8);
  bhalf8 bQ1 = *(const bhalf8*)(Q + (size_t)(q0 + l16) * CC + 32 + lg * 8);
  bhalf8 bQ2 = *(const bhalf8*)(Q + (size_t)(q0 + 16 + l16) * CC + lg * 8);
  bhalf8 bQ3 = *(const bhalf8*)(Q + (size_t)(q0 + 16 + l16) * CC + 32 + lg * 8);

  int r8 = lane >> 3, chn = lane & 7;
  int sch = chn ^ r8;
  const unsigned short* Ksrc = K + (size_t)(8 * wid + r8) * CC + sch * 8;
  const unsigned short* Vsrc = V + (size_t)(8 * wid + r8) * NN + sch * 8;
  unsigned short* KtW = &Kt[0] + (8 * wid) * 64;
  unsigned short* VlW = &Vl[0] + (8 * wid) * 64;

  f32x4 acc0[4], acc1[4];
#pragma unroll
  for (int i = 0; i < 4; i++) {
    acc0[i] = (f32x4){0.f, 0.f, 0.f, 0.f};
    acc1[i] = (f32x4){0.f, 0.f, 0.f, 0.f};
  }
  float m = -1e30f, Lp0 = 0.f, Lp1 = 0.f;
  int sw8 = (l16 & 7) * 8;

  auto stage = [&](int kv0) {
    gload16(Ksrc + (size_t)kv0 * CC, KtW);
    gload16(Vsrc + kv0, VlW);
  };

  auto body = [&]() {
    const unsigned short* Kb_ = &Kt[0];
    const unsigned short* Vb_ = &Vl[0];
    f32x4 St[4], Su[4];
    __builtin_amdgcn_s_setprio(1);
#pragma unroll
    for (int t = 0; t < 4; t++) {
      const unsigned short* kr = Kb_ + (16 * t + l16) * 64;
      bhalf8 aK0 = *(const bhalf8*)(kr + ((lg * 8) ^ sw8));
      bhalf8 aK1 = *(const bhalf8*)(kr + (((lg + 4) * 8) ^ sw8));
      f32x4 sa = (f32x4){0.f, 0.f, 0.f, 0.f};
      f32x4 sb = (f32x4){0.f, 0.f, 0.f, 0.f};
      sa = __builtin_amdgcn_mfma_f32_16x16x32_bf16(aK0, bQ0, sa, 0, 0, 0);
      sa = __builtin_amdgcn_mfma_f32_16x16x32_bf16(aK1, bQ1, sa, 0, 0, 0);
      sb = __builtin_amdgcn_mfma_f32_16x16x32_bf16(aK0, bQ2, sb, 0, 0, 0);
      sb = __builtin_amdgcn_mfma_f32_16x16x32_bf16(aK1, bQ3, sb, 0, 0, 0);
      St[t] = sa;
      Su[t] = sb;
    }
    __builtin_amdgcn_s_setprio(0);
    float m0a = fmaxf(fmaxf(St[0][0], St[0][1]), fmaxf(St[0][2], St[0][3]));
    float m0b = fmaxf(fmaxf(St[1][0], St[1][1]), fmaxf(St[1][2], St[1][3]));
    float m0c = fmaxf(fmaxf(St[2][0], St[2][1]), fmaxf(St[2][2], St[2][3]));
    float m0d = fmaxf(fmaxf(St[3][0], St[3][1]), fmaxf(St[3][2], St[3][3]));
    float m1a = fmaxf(fmaxf(Su[0][0], Su[0][1]), fmaxf(Su[0][2], Su[0][3]));
    float m1b = fmaxf(fmaxf(Su[1][0], Su[1][1]), fmaxf(Su[1][2], Su[1][3]));
    float m1c = fmaxf(fmaxf(Su[2][0], Su[2][1]), fmaxf(Su[2][2], Su[2][3]));
    float m1d = fmaxf(fmaxf(Su[3][0], Su[3][1]), fmaxf(Su[3][2], Su[3][3]));
    float pm = fmaxf(fmaxf(fmaxf(m0a, m0b), fmaxf(m0c, m0d)),
                     fmaxf(fmaxf(m1a, m1b), fmaxf(m1c, m1d)));
    pm = fmaxf(pm, __shfl_xor(pm, 16));
    pm = fmaxf(pm, __shfl_xor(pm, 32));
    if (!__all(pm <= m + DEFER_THR)) {
      float mn = fmaxf(m, pm);
      float sc = EXP2(m - mn);
      m = mn;
      float scq[4];
#pragma unroll
      for (int r = 0; r < 4; r++) scq[r] = __shfl(sc, 4 * lg + r);
#pragma unroll
      for (int cg = 0; cg < 4; cg++)
#pragma unroll
        for (int r = 0; r < 4; r++) {
          acc0[cg][r] *= scq[r];
          acc1[cg][r] *= scq[r];
        }
      Lp0 *= sc;
      Lp1 *= sc;
    }
#pragma unroll
    for (int t = 0; t < 4; t++)
#pragma unroll
      for (int r = 0; r < 4; r++) {
        float p0 = EXP2(St[t][r] - m);
        float p1 = EXP2(Su[t][r] - m);
        St[t][r] = p0; Su[t][r] = p1;
        Lp0 += p0; Lp1 += p1;
      }
#pragma unroll
    for (int t = 0; t < 4; t++) {
      unsigned int pw0, pw1, pw2, pw3;
      float a0 = St[t][0], a1 = St[t][1], a2 = St[t][2], a3 = St[t][3];
      float b0 = Su[t][0], b1 = Su[t][1], b2 = Su[t][2], b3 = Su[t][3];
      asm("v_cvt_pk_bf16_f32 %0, %1, %2" : "=v"(pw0) : "v"(a0), "v"(a1));
      asm("v_cvt_pk_bf16_f32 %0, %1, %2" : "=v"(pw1) : "v"(a2), "v"(a3));
      asm("v_cvt_pk_bf16_f32 %0, %1, %2" : "=v"(pw2) : "v"(b0), "v"(b1));
      asm("v_cvt_pk_bf16_f32 %0, %1, %2" : "=v"(pw3) : "v"(b2), "v"(b3));
      *(uint2*)&Plds[wid][l16][16 * t + 4 * lg] = make_uint2(pw0, pw1);
      *(uint2*)&Plds[wid][16 + l16][16 * t + 4 * lg] = make_uint2(pw2, pw3);
    }
#pragma unroll
    for (int ch = 0; ch < 2; ch++) {
      bhalf8 aP0 = *(bhalf8*)&Plds[wid][l16][ch * 32 + lg * 8];
      bhalf8 aP1 = *(bhalf8*)&Plds[wid][16 + l16][ch * 32 + lg * 8];
      __builtin_amdgcn_s_setprio(1);
#pragma unroll
      for (int cg = 0; cg < 4; cg++) {
        bhalf8 bV = *(const bhalf8*)(Vb_ + (cg * 16 + l16) * 64 +
                                     (((4 * ch + lg) * 8) ^ sw8));
        acc0[cg] = __builtin_amdgcn_mfma_f32_16x16x32_bf16(aP0, bV, acc0[cg], 0, 0, 0);
        acc1[cg] = __builtin_amdgcn_mfma_f32_16x16x32_bf16(aP1, bV, acc1[cg], 0, 0, 0);
      }
      __builtin_amdgcn_s_setprio(0);
    }
  };

  const int nstep = KVPS / 64;  // 8
  for (int stp = 0; stp < nstep; stp++) {
    stage(kvbeg + stp * 64);
    __syncthreads();  // drains vmcnt -> staged data visible to all waves
    body();
    __syncthreads();  // all waves done reading before next overwrite
  }
  size_t rowb = ((size_t)s * BB + b) * NN;
#pragma unroll
  for (int cg = 0; cg < 4; cg++)
#pragma unroll
    for (int r = 0; r < 4; r++) {
      OPb[(rowb + q0 + 4 * lg + r) * CC + cg * 16 + l16] = f2bf(acc0[cg][r]);
      OPb[(rowb + q0 + 16 + 4 * lg + r) * CC + cg * 16 + l16] = f2bf(acc1[cg][r]);
    }
  Lp0 += __shfl_xor(Lp0, 16);
  Lp0 += __shfl_xor(Lp0, 32);
  Lp1 += __shfl_xor(Lp1, 16);
  Lp1 += __shfl_xor(Lp1, 32);
  if (lg == 0) {
    Mb[rowb + q0 + l16] = m;
    Lb[rowb + q0 + l16] = Lp0;
    Mb[rowb + q0 + 16 + l16] = m;
    Lb[rowb + q0 + 16 + l16] = Lp1;
  }
}

// ---- combine + residual + LN2 + FFN; 32 points/block (2 blocks/CU) --------
__global__ __launch_bounds__(256) void ffn_kernel(
    const unsigned short* __restrict__ OPb, const float* __restrict__ Mb,
    const float* __restrict__ Lb, const float* __restrict__ g_in,
    const float* __restrict__ w1, const float* __restrict__ w2,
    const float* __restrict__ b1, const float* __restrict__ b2,
    const float* __restrict__ n2g, const float* __restrict__ n2b,
    float* __restrict__ upd) {
  __shared__ unsigned short Atile[32][72];
  __shared__ unsigned short Htile[32][72];
  __shared__ float aT[32][66];
  __shared__ unsigned short W1[64][72], W2[64][72];
  int tid = threadIdx.x, wid = tid >> 6, lane = tid & 63;
  int l16 = lane & 15, lg = lane >> 4;
  int pt0 = blockIdx.x * 32;

  {
    int c = tid >> 2, k0 = (tid & 3) * 16;
#pragma unroll
    for (int mmm = 0; mmm < 2; mmm++) {
      const float* src = (mmm == 0 ? w1 : w2) + c * 64 + k0;
      unsigned int pk[8];
#pragma unroll
      for (int j = 0; j < 8; j++) {
        float lo = src[2 * j], hi = src[2 * j + 1];
        asm("v_cvt_pk_bf16_f32 %0, %1, %2" : "=v"(pk[j]) : "v"(lo), "v"(hi));
      }
      unsigned short(*Wm)[72] = mmm == 0 ? W1 : W2;
      unsigned int* dst = (unsigned int*)&Wm[c][k0];
      *(uint4*)dst = make_uint4(pk[0], pk[1], pk[2], pk[3]);
      *(uint4*)(dst + 4) = make_uint4(pk[4], pk[5], pk[6], pk[7]);
    }
  }

  float n2g_l = n2g[lane], n2b_l = n2b[lane];
#pragma unroll 2
  for (int i = 0; i < 8; i++) {
    int p = wid * 8 + i;
    int pt = pt0 + p;
    float M = -1e30f;
    float mv[SPLIT];
#pragma unroll
    for (int s = 0; s < SPLIT; s++) {
      mv[s] = Mb[s * (BB * NN) + pt];
      M = fmaxf(M, mv[s]);
    }
    float accv = 0.f, Ls = 0.f;
#pragma unroll
    for (int s = 0; s < SPLIT; s++) {
      float w = EXP2(mv[s] - M);
      accv += w * bf2f(OPb[((size_t)s * (BB * NN) + pt) * CC + lane]);
      Ls += w * Lb[s * (BB * NN) + pt];
    }
    float a = accv / Ls + g_in[(size_t)pt * CC + lane];
    aT[p][lane] = a;
    float s2 = a;
    for (int mm2 = 1; mm2 <= 32; mm2 <<= 1) s2 += __shfl_xor(s2, mm2);
    float mean = s2 * (1.f / 64.f);
    float d = a - mean;
    float vsum = d * d;
    for (int mm2 = 1; mm2 <= 32; mm2 <<= 1) vsum += __shfl_xor(vsum, mm2);
    float rstd = rsqrtf(vsum * (1.f / 64.f) + 1e-5f);
    Atile[p][lane] = f2bf(d * rstd * n2g_l + n2b_l);
  }
  __syncthreads();

  // GEMM1: 8 jobs (2 tiles x 4 ct) over 4 waves
#pragma unroll
  for (int j = 0; j < 2; j++) {
    int job = wid * 2 + j;
    int t = job >> 2, ct = job & 3;
    bhalf8 aH0 = *(bhalf8*)&Atile[t * 16 + l16][lg * 8];
    bhalf8 aH1 = *(bhalf8*)&Atile[t * 16 + l16][32 + lg * 8];
    bhalf8 bw0 = *(bhalf8*)&W1[ct * 16 + l16][lg * 8];
    bhalf8 bw1 = *(bhalf8*)&W1[ct * 16 + l16][32 + lg * 8];
    float b1v = b1[ct * 16 + l16];
    f32x4 d1 = (f32x4){0.f, 0.f, 0.f, 0.f};
    d1 = __builtin_amdgcn_mfma_f32_16x16x32_bf16(aH0, bw0, d1, 0, 0, 0);
    d1 = __builtin_amdgcn_mfma_f32_16x16x32_bf16(aH1, bw1, d1, 0, 0, 0);
#pragma unroll
    for (int r = 0; r < 4; r++) {
      float h = d1[r] + b1v;
      h = 0.5f * h * (1.f + erff(h * 0.70710678118654752f));
      Htile[t * 16 + 4 * lg + r][ct * 16 + l16] = f2bf(h);
    }
  }
  __syncthreads();

  // GEMM2: 8 jobs over 4 waves
#pragma unroll
  for (int j = 0; j < 2; j++) {
    int job = wid * 2 + j;
    int t = job >> 2, ct = job & 3;
    bhalf8 aF0 = *(bhalf8*)&Htile[t * 16 + l16][lg * 8];
    bhalf8 aF1 = *(bhalf8*)&Htile[t * 16 + l16][32 + lg * 8];
    bhalf8 bw0 = *(bhalf8*)&W2[ct * 16 + l16][lg * 8];
    bhalf8 bw1 = *(bhalf8*)&W2[ct * 16 + l16][32 + lg * 8];
    float b2v = b2[ct * 16 + l16];
    f32x4 d2 = (f32x4){0.f, 0.f, 0.f, 0.f};
    d2 = __builtin_amdgcn_mfma_f32_16x16x32_bf16(aF0, bw0, d2, 0, 0, 0);
    d2 = __builtin_amdgcn_mfma_f32_16x16x32_bf16(aF1, bw1, d2, 0, 0, 0);
#pragma unroll
    for (int r = 0; r < 4; r++) {
      int p = t * 16 + 4 * lg + r;
      upd[(size_t)(pt0 + p) * CC + ct * 16 + l16] = d2[r] + b2v + aT[p][ct * 16 + l16];
    }
  }
}

// ---------------- dense output write: zeros + scattered rows, one pass -----
__global__ __launch_bounds__(256) void out_kernel(
    const int* __restrict__ map, const float* __restrict__ upd,
    float* __restrict__ out) {
  int b = blockIdx.x / (HW_ / 256);
  int pos = (blockIdx.x % (HW_ / 256)) * 256 + threadIdx.x;
  int r = map[b * HW_ + pos];
  float4 vals[16];
  if (r >= 0) {
    const float4* up = (const float4*)(upd + ((size_t)b * NN + r) * CC);
#pragma unroll
    for (int i = 0; i < 16; i++) vals[i] = up[i];
  } else {
#pragma unroll
    for (int i = 0; i < 16; i++) vals[i] = make_float4(0.f, 0.f, 0.f, 0.f);
  }
  float* o = out + (size_t)b * CC * HW_ + pos;
#pragma unroll
  for (int i = 0; i < 16; i++) {
    o[(size_t)(4 * i + 0) * HW_] = vals[i].x;
    o[(size_t)(4 * i + 1) * HW_] = vals[i].y;
    o[(size_t)(4 * i + 2) * HW_] = vals[i].z;
    o[(size_t)(4 * i + 3) * HW_] = vals[i].w;
  }
}

extern "C" void kernel_launch(void* const* d_in, const int* in_sizes, int n_in,
                              void* d_out, int out_size, void* d_ws, size_t ws_size,
                              hipStream_t stream) {
  const float* pillar = (const float*)d_in[0];
  const int* vidx = (const int*)d_in[1];
  const float* qw = (const float*)d_in[2];
  const float* qb = (const float*)d_in[3];
  const float* kw = (const float*)d_in[4];
  const float* kb = (const float*)d_in[5];
  const float* vw = (const float*)d_in[6];
  const float* vb = (const float*)d_in[7];
  const float* w1 = (const float*)d_in[8];
  const float* b1 = (const float*)d_in[9];
  const float* w2 = (const float*)d_in[10];
  const float* b2 = (const float*)d_in[11];
  const float* n1g = (const float*)d_in[12];
  const float* n1b = (const float*)d_in[13];
  const float* n2g = (const float*)d_in[14];
  const float* n2b = (const float*)d_in[15];
  float* out = (float*)d_out;

  char* ws = (char*)d_ws;
  size_t off = 0;
  auto take = [&](size_t bytes) -> char* {
    off = (off + 255) & ~(size_t)255;
    char* p = ws + off;
    off += bytes;
    return p;
  };
  float* tabHS = (float*)take((size_t)HH * 32 * 4);
  float* tabHC = (float*)take((size_t)HH * 32 * 4);
  float* tabWS = (float*)take((size_t)WW * 32 * 4);
  float* tabWC = (float*)take((size_t)WW * 32 * 4);
  float* gbuf = (float*)take((size_t)BB * NN * CC * 4);
  float* updb = (float*)take((size_t)BB * NN * CC * 4);
  unsigned short* Qb = (unsigned short*)take((size_t)BB * NN * CC * 2);
  unsigned short* Kb = (unsigned short*)take((size_t)BB * NN * CC * 2);
  unsigned short* Vt = (unsigned short*)take((size_t)BB * CC * NN * 2);
  unsigned short* OPb = (unsigned short*)take((size_t)SPLIT * BB * NN * CC * 2);
  float* Mbuf = (float*)take((size_t)SPLIT * BB * NN * 4);
  float* Lbuf = (float*)take((size_t)SPLIT * BB * NN * 4);
  int* map = (int*)take((size_t)BB * HW_ * 4);

  int preptot = (HH + WW) * 32 + BB * HW_;
  prep_kernel<<<(preptot + 255) / 256, 256, 0, stream>>>(
      tabHS, tabHC, tabWS, tabWC, map);
  qkv_kernel<<<BB * NN / 32, 256, 0, stream>>>(
      pillar, vidx, tabHS, tabHC, tabWS, tabWC, qw, kw, vw, qb, kb, vb,
      n1g, n1b, gbuf, Qb, Kb, Vt, map);
  attn_kernel<<<BB * (NN / 256) * SPLIT, 512, 0, stream>>>(Qb, Kb, Vt, OPb, Mbuf, Lbuf);
  ffn_kernel<<<BB * NN / 32, 256, 0, stream>>>(OPb, Mbuf, Lbuf, gbuf, w1, w2,
                                               b1, b2, n2g, n2b, updb);
  out_kernel<<<BB * (HW_ / 256), 256, 0, stream>>>(map, updb, out);
}

// Round 16
// 99.153 us; speedup vs baseline: 2.5934x; 1.0546x over previous
//
#include <hip/hip_runtime.h>
#include <hip/hip_bf16.h>
#include <math.h>

#define HH 496
#define WW 432
#define CC 64
#define BB 2
#define NN 8192
#define HW_ (HH * WW)
#define SPLIT 8
#define KVPS (NN / SPLIT)  // 1024 kv per split
#define LOG2E 1.44269504088896f
#define DEFER_THR 11.541560327f  // 8 * log2(e), log2-domain defer-max threshold
#define NB4 ((HW_ + 1023) / 1024)  // out_kernel blocks per batch (4 pos/thread)

#if __has_builtin(__builtin_amdgcn_exp2f)
#define EXP2(x) __builtin_amdgcn_exp2f(x)
#else
#define EXP2(x) exp2f(x)
#endif

typedef __attribute__((ext_vector_type(8))) short bhalf8;
typedef __attribute__((ext_vector_type(4))) float f32x4;

__device__ __forceinline__ unsigned short f2bf(float f) {
  union { float f; unsigned int u; } v; v.f = f;
  unsigned int r = (v.u + 0x7fffu + ((v.u >> 16) & 1u)) >> 16;
  return (unsigned short)r;
}

__device__ __forceinline__ float bf2f(unsigned short u) {
  union { unsigned int u; float f; } v;
  v.u = ((unsigned int)u) << 16;
  return v.f;
}

__device__ __forceinline__ void gload16(const void* g, void* l) {
  __builtin_amdgcn_global_load_lds(
      (const __attribute__((address_space(1))) void*)g,
      (__attribute__((address_space(3))) void*)l, 16, 0, 0);
}

// ---------------- sin/cos tables + map init ----------------
__global__ void prep_kernel(float* __restrict__ tabHS, float* __restrict__ tabHC,
                            float* __restrict__ tabWS, float* __restrict__ tabWC,
                            int* __restrict__ map) {
  int tid = blockIdx.x * blockDim.x + threadIdx.x;
  const int ntab = (HH + WW) * 32;
  if (tid < ntab) {
    int j = tid & 31;
    float theta = __expf(-(float)j * (9.210340371976184f / 32.f));
    if (tid < HH * 32) {
      int i = tid >> 5;
      float h = -1.f + 2.f * (float)i / (float)(HH - 1);
      float a = h * theta;
      tabHS[tid] = sinf(a);
      tabHC[tid] = cosf(a);
    } else {
      int t2 = tid - HH * 32;
      int i = t2 >> 5;
      float w = -1.f + 2.f * (float)i / (float)(WW - 1);
      float a = w * theta;
      tabWS[t2] = sinf(a);
      tabWC[t2] = cosf(a);
    }
  } else if (tid < ntab + BB * HW_) {
    map[tid - ntab] = -1;
  }
}

// ------ gather + RoPE + LN1 + QKV via MFMA; 32 points/block (2 blocks/CU) ---
__global__ __launch_bounds__(256) void qkv_kernel(
    const float* __restrict__ pillar, const int* __restrict__ vidx,
    const float* __restrict__ tabHS, const float* __restrict__ tabHC,
    const float* __restrict__ tabWS, const float* __restrict__ tabWC,
    const float* __restrict__ qw, const float* __restrict__ kw,
    const float* __restrict__ vw,
    const float* __restrict__ qb, const float* __restrict__ kbias,
    const float* __restrict__ vb,
    const float* __restrict__ n1g, const float* __restrict__ n1b,
    float* __restrict__ g_out, unsigned short* __restrict__ Qb,
    unsigned short* __restrict__ Kb, unsigned short* __restrict__ Vt,
    int* __restrict__ map) {
  __shared__ unsigned short Aln[32][72];
  __shared__ unsigned short Wq[64][72], Wk[64][72], Wv[64][72];
  __shared__ unsigned int Vbo[64][20];  // V bounce [c][point-pair], 16 used
  int tid = threadIdx.x, wid = tid >> 6, lane = tid & 63;
  int l16 = lane & 15, lg = lane >> 4;
  int pt0 = blockIdx.x * 32;
  int b = pt0 >> 13, n0 = pt0 & (NN - 1);

  // stage weights (bf16, rows [c][k])
  {
    int c = tid >> 2, k0 = (tid & 3) * 16;
#pragma unroll
    for (int mmm = 0; mmm < 3; mmm++) {
      const float* src = (mmm == 0 ? qw : mmm == 1 ? kw : vw) + c * 64 + k0;
      unsigned int pk[8];
#pragma unroll
      for (int j = 0; j < 8; j++) {
        float lo = src[2 * j], hi = src[2 * j + 1];
        asm("v_cvt_pk_bf16_f32 %0, %1, %2" : "=v"(pk[j]) : "v"(lo), "v"(hi));
      }
      unsigned short(*Wm)[72] = mmm == 0 ? Wq : mmm == 1 ? Wk : Wv;
      unsigned int* dst = (unsigned int*)&Wm[c][k0];
      *(uint4*)dst = make_uint4(pk[0], pk[1], pk[2], pk[3]);
      *(uint4*)(dst + 4) = make_uint4(pk[4], pk[5], pk[6], pk[7]);
    }
  }

  // phase 1: RoPE + LN1, 8 points per wave
  float n1g_l = n1g[lane], n1b_l = n1b[lane];
#pragma unroll 4
  for (int i = 0; i < 8; i++) {
    int p = wid * 8 + i;
    int pt = pt0 + p;
    float x = pillar[(size_t)pt * CC + lane];
    int pos = vidx[pt];
    int h = pos / WW, w = pos - h * WW;
    int j = lane & 31;
    float x1 = __shfl(x, j), x2 = __shfl(x, j + 32);
    float hs = tabHS[h * 32 + j], hc = tabHC[h * 32 + j];
    float ws = tabWS[w * 32 + j], wc = tabWC[w * 32 + j];
    float rope = (lane < 32) ? (x1 * hc * wc - x2 * hs * ws)
                             : (x1 * hs * ws + x2 * hc * wc);
    float gv = x + rope;
    g_out[(size_t)pt * CC + lane] = gv;
    float s = gv;
    for (int mm2 = 1; mm2 <= 32; mm2 <<= 1) s += __shfl_xor(s, mm2);
    float mean = s * (1.f / 64.f);
    float d = gv - mean;
    float vsum = d * d;
    for (int mm2 = 1; mm2 <= 32; mm2 <<= 1) vsum += __shfl_xor(vsum, mm2);
    float rstd = rsqrtf(vsum * (1.f / 64.f) + 1e-5f);
    float gn = d * rstd * n1g_l + n1b_l;
    Aln[p][lane] = f2bf(gn);
    if (lane == 0) map[b * HW_ + pos] = pt & (NN - 1);
  }
  __syncthreads();

  // phase 2: 24 MFMA jobs (2 tiles x 3 matrices x 4 ct) over 4 waves
#pragma unroll
  for (int j = 0; j < 6; j++) {
    int job = wid * 6 + j;
    int t = job / 12;
    int rem = job % 12;
    int mat = rem >> 2;
    int ct = rem & 3;
    bhalf8 aG0 = *(bhalf8*)&Aln[t * 16 + l16][lg * 8];
    bhalf8 aG1 = *(bhalf8*)&Aln[t * 16 + l16][32 + lg * 8];
    unsigned short(*Wm)[72] = mat == 0 ? Wq : mat == 1 ? Wk : Wv;
    bhalf8 bw0 = *(bhalf8*)&Wm[ct * 16 + l16][lg * 8];
    bhalf8 bw1 = *(bhalf8*)&Wm[ct * 16 + l16][32 + lg * 8];
    const float* bptr = mat == 0 ? qb : mat == 1 ? kbias : vb;
    float bias = bptr[ct * 16 + l16];
    f32x4 d = (f32x4){0.f, 0.f, 0.f, 0.f};
    d = __builtin_amdgcn_mfma_f32_16x16x32_bf16(aG0, bw0, d, 0, 0, 0);
    d = __builtin_amdgcn_mfma_f32_16x16x32_bf16(aG1, bw1, d, 0, 0, 0);
    if (mat == 0) {
#pragma unroll
      for (int r = 0; r < 4; r++) {
        size_t gi = (size_t)(pt0 + t * 16 + 4 * lg + r) * CC + ct * 16 + l16;
        Qb[gi] = f2bf((d[r] + bias) * LOG2E);  // log2-domain pre-scale
      }
    } else if (mat == 1) {
#pragma unroll
      for (int r = 0; r < 4; r++) {
        size_t gi = (size_t)(pt0 + t * 16 + 4 * lg + r) * CC + ct * 16 + l16;
        Kb[gi] = f2bf(d[r] + bias);
      }
    } else {
      float e0 = d[0] + bias, e1 = d[1] + bias;
      float e2 = d[2] + bias, e3 = d[3] + bias;
      unsigned int v0, v1;
      asm("v_cvt_pk_bf16_f32 %0, %1, %2" : "=v"(v0) : "v"(e0), "v"(e1));
      asm("v_cvt_pk_bf16_f32 %0, %1, %2" : "=v"(v1) : "v"(e2), "v"(e3));
      Vbo[ct * 16 + l16][t * 8 + 2 * lg + 0] = v0;
      Vbo[ct * 16 + l16][t * 8 + 2 * lg + 1] = v1;
    }
  }
  __syncthreads();
  // V write-out: coalesced rows of Vt[b][c][n]
  {
    int c = tid >> 2, ch = tid & 3;
    uint4 w0 = *(uint4*)&Vbo[c][ch * 4];
    *(uint4*)(Vt + ((size_t)b * CC + c) * NN + n0 + ch * 8) = w0;
  }
}

// ------- flash attention: 8 waves x 32 q-rows (exact R12/R9 config) --------
__global__ __attribute__((amdgpu_flat_work_group_size(512, 512),
                          amdgpu_waves_per_eu(4, 4))) void attn_kernel(
    const unsigned short* __restrict__ Qb, const unsigned short* __restrict__ Kb,
    const unsigned short* __restrict__ Vt,
    unsigned short* __restrict__ OPb, float* __restrict__ Mb,
    float* __restrict__ Lb) {
  __shared__ unsigned short Kt[2][64 * 64];
  __shared__ unsigned short Vl[2][64 * 64];
  __shared__ unsigned short Plds[8][32][72];
  int tidx = threadIdx.x;
  int wid = tidx >> 6, lane = tidx & 63;
  int l16 = lane & 15, lg = lane >> 4;
  int blk = blockIdx.x;
  int s = blk & (SPLIT - 1);
  int tb = blk >> 3;
  int b = tb >> 5;
  int tile = tb & 31;
  int q0 = tile * 256 + wid * 32;
  int kvbeg = s * KVPS;
  const unsigned short* Q = Qb + (size_t)b * NN * CC;
  const unsigned short* K = Kb + (size_t)b * NN * CC;
  const unsigned short* V = Vt + (size_t)b * CC * NN;

  bhalf8 bQ0 = *(const bhalf8*)(Q + (size_t)(q0 + l16) * CC + lg * 8);
  bhalf8 bQ1 = *(const bhalf8*)(Q + (size_t)(q0 + l16) * CC + 32 + lg * 8);
  bhalf8 bQ2 = *(const bhalf8*)(Q + (size_t)(q0 + 16 + l16) * CC + lg * 8);
  bhalf8 bQ3 = *(const bhalf8*)(Q + (size_t)(q0 + 16 + l16) * CC + 32 + lg * 8);

  int r8 = lane >> 3, chn = lane & 7;
  int sch = chn ^ r8;
  const unsigned short* Ksrc = K + (size_t)(8 * wid + r8) * CC + sch * 8;
  const unsigned short* Vsrc = V + (size_t)(8 * wid + r8) * NN + sch * 8;
  unsigned short* KtW = &Kt[0][0] + (8 * wid) * 64;
  unsigned short* VlW = &Vl[0][0] + (8 * wid) * 64;

  f32x4 acc0[4], acc1[4];
#pragma unroll
  for (int i = 0; i < 4; i++) {
    acc0[i] = (f32x4){0.f, 0.f, 0.f, 0.f};
    acc1[i] = (f32x4){0.f, 0.f, 0.f, 0.f};
  }
  float m = -1e30f, Lp0 = 0.f, Lp1 = 0.f;
  int sw8 = (l16 & 7) * 8;

  auto stage = [&](int bufi, int kv0) {
    gload16(Ksrc + (size_t)kv0 * CC, KtW + bufi * 4096);
    gload16(Vsrc + kv0, VlW + bufi * 4096);
  };

  auto body = [&](int buf, int kv0) {
    const unsigned short* Kb_ = &Kt[buf][0];
    const unsigned short* Vb_ = &Vl[buf][0];
    f32x4 St[4], Su[4];
    __builtin_amdgcn_s_setprio(1);
#pragma unroll
    for (int t = 0; t < 4; t++) {
      const unsigned short* kr = Kb_ + (16 * t + l16) * 64;
      bhalf8 aK0 = *(const bhalf8*)(kr + ((lg * 8) ^ sw8));
      bhalf8 aK1 = *(const bhalf8*)(kr + (((lg + 4) * 8) ^ sw8));
      f32x4 sa = (f32x4){0.f, 0.f, 0.f, 0.f};
      f32x4 sb = (f32x4){0.f, 0.f, 0.f, 0.f};
      sa = __builtin_amdgcn_mfma_f32_16x16x32_bf16(aK0, bQ0, sa, 0, 0, 0);
      sa = __builtin_amdgcn_mfma_f32_16x16x32_bf16(aK1, bQ1, sa, 0, 0, 0);
      sb = __builtin_amdgcn_mfma_f32_16x16x32_bf16(aK0, bQ2, sb, 0, 0, 0);
      sb = __builtin_amdgcn_mfma_f32_16x16x32_bf16(aK1, bQ3, sb, 0, 0, 0);
      St[t] = sa;
      Su[t] = sb;
    }
    __builtin_amdgcn_s_setprio(0);
    float m0a = fmaxf(fmaxf(St[0][0], St[0][1]), fmaxf(St[0][2], St[0][3]));
    float m0b = fmaxf(fmaxf(St[1][0], St[1][1]), fmaxf(St[1][2], St[1][3]));
    float m0c = fmaxf(fmaxf(St[2][0], St[2][1]), fmaxf(St[2][2], St[2][3]));
    float m0d = fmaxf(fmaxf(St[3][0], St[3][1]), fmaxf(St[3][2], St[3][3]));
    float m1a = fmaxf(fmaxf(Su[0][0], Su[0][1]), fmaxf(Su[0][2], Su[0][3]));
    float m1b = fmaxf(fmaxf(Su[1][0], Su[1][1]), fmaxf(Su[1][2], Su[1][3]));
    float m1c = fmaxf(fmaxf(Su[2][0], Su[2][1]), fmaxf(Su[2][2], Su[2][3]));
    float m1d = fmaxf(fmaxf(Su[3][0], Su[3][1]), fmaxf(Su[3][2], Su[3][3]));
    float pm = fmaxf(fmaxf(fmaxf(m0a, m0b), fmaxf(m0c, m0d)),
                     fmaxf(fmaxf(m1a, m1b), fmaxf(m1c, m1d)));
    pm = fmaxf(pm, __shfl_xor(pm, 16));
    pm = fmaxf(pm, __shfl_xor(pm, 32));
    if (!__all(pm <= m + DEFER_THR)) {
      float mn = fmaxf(m, pm);
      float sc = EXP2(m - mn);
      m = mn;
      float scq[4];
#pragma unroll
      for (int r = 0; r < 4; r++) scq[r] = __shfl(sc, 4 * lg + r);
#pragma unroll
      for (int cg = 0; cg < 4; cg++)
#pragma unroll
        for (int r = 0; r < 4; r++) {
          acc0[cg][r] *= scq[r];
          acc1[cg][r] *= scq[r];
        }
      Lp0 *= sc;
      Lp1 *= sc;
    }
#pragma unroll
    for (int t = 0; t < 4; t++)
#pragma unroll
      for (int r = 0; r < 4; r++) {
        float p0 = EXP2(St[t][r] - m);
        float p1 = EXP2(Su[t][r] - m);
        St[t][r] = p0; Su[t][r] = p1;
        Lp0 += p0; Lp1 += p1;
      }
#pragma unroll
    for (int t = 0; t < 4; t++) {
      unsigned int pw0, pw1, pw2, pw3;
      float a0 = St[t][0], a1 = St[t][1], a2 = St[t][2], a3 = St[t][3];
      float b0 = Su[t][0], b1 = Su[t][1], b2 = Su[t][2], b3 = Su[t][3];
      asm("v_cvt_pk_bf16_f32 %0, %1, %2" : "=v"(pw0) : "v"(a0), "v"(a1));
      asm("v_cvt_pk_bf16_f32 %0, %1, %2" : "=v"(pw1) : "v"(a2), "v"(a3));
      asm("v_cvt_pk_bf16_f32 %0, %1, %2" : "=v"(pw2) : "v"(b0), "v"(b1));
      asm("v_cvt_pk_bf16_f32 %0, %1, %2" : "=v"(pw3) : "v"(b2), "v"(b3));
      *(uint2*)&Plds[wid][l16][16 * t + 4 * lg] = make_uint2(pw0, pw1);
      *(uint2*)&Plds[wid][16 + l16][16 * t + 4 * lg] = make_uint2(pw2, pw3);
    }
#pragma unroll
    for (int ch = 0; ch < 2; ch++) {
      bhalf8 aP0 = *(bhalf8*)&Plds[wid][l16][ch * 32 + lg * 8];
      bhalf8 aP1 = *(bhalf8*)&Plds[wid][16 + l16][ch * 32 + lg * 8];
      __builtin_amdgcn_s_setprio(1);
#pragma unroll
      for (int cg = 0; cg < 4; cg++) {
        bhalf8 bV = *(const bhalf8*)(Vb_ + (cg * 16 + l16) * 64 +
                                     (((4 * ch + lg) * 8) ^ sw8));
        acc0[cg] = __builtin_amdgcn_mfma_f32_16x16x32_bf16(aP0, bV, acc0[cg], 0, 0, 0);
        acc1[cg] = __builtin_amdgcn_mfma_f32_16x16x32_bf16(aP1, bV, acc1[cg], 0, 0, 0);
      }
      __builtin_amdgcn_s_setprio(0);
    }
  };

  stage(0, kvbeg);
  __syncthreads();
  const int nstep = KVPS / 64;  // 16, even
  for (int stp = 0; stp < nstep; stp += 2) {
    int kv0 = kvbeg + stp * 64;
    if (stp + 1 < nstep) stage(1, kv0 + 64);
    body(0, kv0);
    __syncthreads();
    if (stp + 2 < nstep) stage(0, kv0 + 128);
    body(1, kv0 + 64);
    __syncthreads();
  }
  size_t rowb = ((size_t)s * BB + b) * NN;
#pragma unroll
  for (int cg = 0; cg < 4; cg++)
#pragma unroll
    for (int r = 0; r < 4; r++) {
      OPb[(rowb + q0 + 4 * lg + r) * CC + cg * 16 + l16] = f2bf(acc0[cg][r]);
      OPb[(rowb + q0 + 16 + 4 * lg + r) * CC + cg * 16 + l16] = f2bf(acc1[cg][r]);
    }
  Lp0 += __shfl_xor(Lp0, 16);
  Lp0 += __shfl_xor(Lp0, 32);
  Lp1 += __shfl_xor(Lp1, 16);
  Lp1 += __shfl_xor(Lp1, 32);
  if (lg == 0) {
    Mb[rowb + q0 + l16] = m;
    Lb[rowb + q0 + l16] = Lp0;
    Mb[rowb + q0 + 16 + l16] = m;
    Lb[rowb + q0 + 16 + l16] = Lp1;
  }
}

// ---- combine + residual + LN2 + FFN; 32 points/block (2 blocks/CU) --------
__global__ __launch_bounds__(256) void ffn_kernel(
    const unsigned short* __restrict__ OPb, const float* __restrict__ Mb,
    const float* __restrict__ Lb, const float* __restrict__ g_in,
    const float* __restrict__ w1, const float* __restrict__ w2,
    const float* __restrict__ b1, const float* __restrict__ b2,
    const float* __restrict__ n2g, const float* __restrict__ n2b,
    float* __restrict__ upd) {
  __shared__ unsigned short Atile[32][72];
  __shared__ unsigned short Htile[32][72];
  __shared__ float aT[32][66];
  __shared__ unsigned short W1[64][72], W2[64][72];
  int tid = threadIdx.x, wid = tid >> 6, lane = tid & 63;
  int l16 = lane & 15, lg = lane >> 4;
  int pt0 = blockIdx.x * 32;

  {
    int c = tid >> 2, k0 = (tid & 3) * 16;
#pragma unroll
    for (int mmm = 0; mmm < 2; mmm++) {
      const float* src = (mmm == 0 ? w1 : w2) + c * 64 + k0;
      unsigned int pk[8];
#pragma unroll
      for (int j = 0; j < 8; j++) {
        float lo = src[2 * j], hi = src[2 * j + 1];
        asm("v_cvt_pk_bf16_f32 %0, %1, %2" : "=v"(pk[j]) : "v"(lo), "v"(hi));
      }
      unsigned short(*Wm)[72] = mmm == 0 ? W1 : W2;
      unsigned int* dst = (unsigned int*)&Wm[c][k0];
      *(uint4*)dst = make_uint4(pk[0], pk[1], pk[2], pk[3]);
      *(uint4*)(dst + 4) = make_uint4(pk[4], pk[5], pk[6], pk[7]);
    }
  }

  float n2g_l = n2g[lane], n2b_l = n2b[lane];
#pragma unroll 2
  for (int i = 0; i < 8; i++) {
    int p = wid * 8 + i;
    int pt = pt0 + p;
    float M = -1e30f;
    float mv[SPLIT];
#pragma unroll
    for (int s = 0; s < SPLIT; s++) {
      mv[s] = Mb[s * (BB * NN) + pt];
      M = fmaxf(M, mv[s]);
    }
    float accv = 0.f, Ls = 0.f;
#pragma unroll
    for (int s = 0; s < SPLIT; s++) {
      float w = EXP2(mv[s] - M);
      accv += w * bf2f(OPb[((size_t)s * (BB * NN) + pt) * CC + lane]);
      Ls += w * Lb[s * (BB * NN) + pt];
    }
    float a = accv / Ls + g_in[(size_t)pt * CC + lane];
    aT[p][lane] = a;
    float s2 = a;
    for (int mm2 = 1; mm2 <= 32; mm2 <<= 1) s2 += __shfl_xor(s2, mm2);
    float mean = s2 * (1.f / 64.f);
    float d = a - mean;
    float vsum = d * d;
    for (int mm2 = 1; mm2 <= 32; mm2 <<= 1) vsum += __shfl_xor(vsum, mm2);
    float rstd = rsqrtf(vsum * (1.f / 64.f) + 1e-5f);
    Atile[p][lane] = f2bf(d * rstd * n2g_l + n2b_l);
  }
  __syncthreads();

  // GEMM1: 8 jobs (2 tiles x 4 ct) over 4 waves
#pragma unroll
  for (int j = 0; j < 2; j++) {
    int job = wid * 2 + j;
    int t = job >> 2, ct = job & 3;
    bhalf8 aH0 = *(bhalf8*)&Atile[t * 16 + l16][lg * 8];
    bhalf8 aH1 = *(bhalf8*)&Atile[t * 16 + l16][32 + lg * 8];
    bhalf8 bw0 = *(bhalf8*)&W1[ct * 16 + l16][lg * 8];
    bhalf8 bw1 = *(bhalf8*)&W1[ct * 16 + l16][32 + lg * 8];
    float b1v = b1[ct * 16 + l16];
    f32x4 d1 = (f32x4){0.f, 0.f, 0.f, 0.f};
    d1 = __builtin_amdgcn_mfma_f32_16x16x32_bf16(aH0, bw0, d1, 0, 0, 0);
    d1 = __builtin_amdgcn_mfma_f32_16x16x32_bf16(aH1, bw1, d1, 0, 0, 0);
#pragma unroll
    for (int r = 0; r < 4; r++) {
      float h = d1[r] + b1v;
      h = 0.5f * h * (1.f + erff(h * 0.70710678118654752f));
      Htile[t * 16 + 4 * lg + r][ct * 16 + l16] = f2bf(h);
    }
  }
  __syncthreads();

  // GEMM2: 8 jobs over 4 waves
#pragma unroll
  for (int j = 0; j < 2; j++) {
    int job = wid * 2 + j;
    int t = job >> 2, ct = job & 3;
    bhalf8 aF0 = *(bhalf8*)&Htile[t * 16 + l16][lg * 8];
    bhalf8 aF1 = *(bhalf8*)&Htile[t * 16 + l16][32 + lg * 8];
    bhalf8 bw0 = *(bhalf8*)&W2[ct * 16 + l16][lg * 8];
    bhalf8 bw1 = *(bhalf8*)&W2[ct * 16 + l16][32 + lg * 8];
    float b2v = b2[ct * 16 + l16];
    f32x4 d2 = (f32x4){0.f, 0.f, 0.f, 0.f};
    d2 = __builtin_amdgcn_mfma_f32_16x16x32_bf16(aF0, bw0, d2, 0, 0, 0);
    d2 = __builtin_amdgcn_mfma_f32_16x16x32_bf16(aF1, bw1, d2, 0, 0, 0);
#pragma unroll
    for (int r = 0; r < 4; r++) {
      int p = t * 16 + 4 * lg + r;
      upd[(size_t)(pt0 + p) * CC + ct * 16 + l16] = d2[r] + b2v + aT[p][ct * 16 + l16];
    }
  }
}

// ------ dense output write: 4 positions/thread, float4 stores (1KB/wave) ---
__global__ __launch_bounds__(256) void out_kernel(
    const int* __restrict__ map, const float* __restrict__ upd,
    float* __restrict__ out) {
  int b = blockIdx.x / NB4;
  int p4 = (blockIdx.x % NB4) * 1024 + threadIdx.x * 4;
  if (p4 >= HW_) return;
  int r0 = map[b * HW_ + p4 + 0];
  int r1 = map[b * HW_ + p4 + 1];
  int r2 = map[b * HW_ + p4 + 2];
  int r3 = map[b * HW_ + p4 + 3];
  const float* base = upd + (size_t)b * NN * CC;
  float* o = out + (size_t)b * CC * HW_ + p4;
  float4 z = make_float4(0.f, 0.f, 0.f, 0.f);
#pragma unroll
  for (int cg = 0; cg < 16; cg++) {
    float4 v0 = (r0 >= 0) ? *(const float4*)(base + (size_t)r0 * CC + cg * 4) : z;
    float4 v1 = (r1 >= 0) ? *(const float4*)(base + (size_t)r1 * CC + cg * 4) : z;
    float4 v2 = (r2 >= 0) ? *(const float4*)(base + (size_t)r2 * CC + cg * 4) : z;
    float4 v3 = (r3 >= 0) ? *(const float4*)(base + (size_t)r3 * CC + cg * 4) : z;
    *(float4*)(o + (size_t)(cg * 4 + 0) * HW_) = make_float4(v0.x, v1.x, v2.x, v3.x);
    *(float4*)(o + (size_t)(cg * 4 + 1) * HW_) = make_float4(v0.y, v1.y, v2.y, v3.y);
    *(float4*)(o + (size_t)(cg * 4 + 2) * HW_) = make_float4(v0.z, v1.z, v2.z, v3.z);
    *(float4*)(o + (size_t)(cg * 4 + 3) * HW_) = make_float4(v0.w, v1.w, v2.w, v3.w);
  }
}

extern "C" void kernel_launch(void* const* d_in, const int* in_sizes, int n_in,
                              void* d_out, int out_size, void* d_ws, size_t ws_size,
                              hipStream_t stream) {
  const float* pillar = (const float*)d_in[0];
  const int* vidx = (const int*)d_in[1];
  const float* qw = (const float*)d_in[2];
  const float* qb = (const float*)d_in[3];
  const float* kw = (const float*)d_in[4];
  const float* kb = (const float*)d_in[5];
  const float* vw = (const float*)d_in[6];
  const float* vb = (const float*)d_in[7];
  const float* w1 = (const float*)d_in[8];
  const float* b1 = (const float*)d_in[9];
  const float* w2 = (const float*)d_in[10];
  const float* b2 = (const float*)d_in[11];
  const float* n1g = (const float*)d_in[12];
  const float* n1b = (const float*)d_in[13];
  const float* n2g = (const float*)d_in[14];
  const float* n2b = (const float*)d_in[15];
  float* out = (float*)d_out;

  char* ws = (char*)d_ws;
  size_t off = 0;
  auto take = [&](size_t bytes) -> char* {
    off = (off + 255) & ~(size_t)255;
    char* p = ws + off;
    off += bytes;
    return p;
  };
  float* tabHS = (float*)take((size_t)HH * 32 * 4);
  float* tabHC = (float*)take((size_t)HH * 32 * 4);
  float* tabWS = (float*)take((size_t)WW * 32 * 4);
  float* tabWC = (float*)take((size_t)WW * 32 * 4);
  float* gbuf = (float*)take((size_t)BB * NN * CC * 4);
  float* updb = (float*)take((size_t)BB * NN * CC * 4);
  unsigned short* Qb = (unsigned short*)take((size_t)BB * NN * CC * 2);
  unsigned short* Kb = (unsigned short*)take((size_t)BB * NN * CC * 2);
  unsigned short* Vt = (unsigned short*)take((size_t)BB * CC * NN * 2);
  unsigned short* OPb = (unsigned short*)take((size_t)SPLIT * BB * NN * CC * 2);
  float* Mbuf = (float*)take((size_t)SPLIT * BB * NN * 4);
  float* Lbuf = (float*)take((size_t)SPLIT * BB * NN * 4);
  int* map = (int*)take((size_t)BB * HW_ * 4);

  int preptot = (HH + WW) * 32 + BB * HW_;
  prep_kernel<<<(preptot + 255) / 256, 256, 0, stream>>>(
      tabHS, tabHC, tabWS, tabWC, map);
  qkv_kernel<<<BB * NN / 32, 256, 0, stream>>>(
      pillar, vidx, tabHS, tabHC, tabWS, tabWC, qw, kw, vw, qb, kb, vb,
      n1g, n1b, gbuf, Qb, Kb, Vt, map);
  attn_kernel<<<BB * (NN / 256) * SPLIT, 512, 0, stream>>>(Qb, Kb, Vt, OPb, Mbuf, Lbuf);
  ffn_kernel<<<BB * NN / 32, 256, 0, stream>>>(OPb, Mbuf, Lbuf, gbuf, w1, w2,
                                               b1, b2, n2g, n2b, updb);
  out_kernel<<<BB * NB4, 256, 0, stream>>>(map, updb, out);
}

// Round 17
// 95.708 us; speedup vs baseline: 2.6868x; 1.0360x over previous
//
#include <hip/hip_runtime.h>
#include <hip/hip_bf16.h>
#include <math.h>

#define HH 496
#define WW 432
#define CC 64
#define BB 2
#define NN 8192
#define HW_ (HH * WW)
#define SPLIT 8
#define KVPS (NN / SPLIT)  // 1024 kv per split
#define LOG2E 1.44269504088896f
#define DEFER_THR 11.541560327f  // 8 * log2(e), log2-domain defer-max threshold
#define NB4 ((HW_ + 1023) / 1024)

#if __has_builtin(__builtin_amdgcn_exp2f)
#define EXP2(x) __builtin_amdgcn_exp2f(x)
#else
#define EXP2(x) exp2f(x)
#endif

typedef __attribute__((ext_vector_type(8))) short bhalf8;
typedef __attribute__((ext_vector_type(4))) float f32x4;

__device__ __forceinline__ unsigned short f2bf(float f) {
  union { float f; unsigned int u; } v; v.f = f;
  unsigned int r = (v.u + 0x7fffu + ((v.u >> 16) & 1u)) >> 16;
  return (unsigned short)r;
}

__device__ __forceinline__ float bf2f(unsigned short u) {
  union { unsigned int u; float f; } v;
  v.u = ((unsigned int)u) << 16;
  return v.f;
}

__device__ __forceinline__ void gload16(const void* g, void* l) {
  __builtin_amdgcn_global_load_lds(
      (const __attribute__((address_space(1))) void*)g,
      (__attribute__((address_space(3))) void*)l, 16, 0, 0);
}

// ---------------- sin/cos tables + map init ----------------
__global__ void prep_kernel(float* __restrict__ tabHS, float* __restrict__ tabHC,
                            float* __restrict__ tabWS, float* __restrict__ tabWC,
                            int* __restrict__ map) {
  int tid = blockIdx.x * blockDim.x + threadIdx.x;
  const int ntab = (HH + WW) * 32;
  if (tid < ntab) {
    int j = tid & 31;
    float theta = __expf(-(float)j * (9.210340371976184f / 32.f));
    if (tid < HH * 32) {
      int i = tid >> 5;
      float h = -1.f + 2.f * (float)i / (float)(HH - 1);
      float a = h * theta;
      tabHS[tid] = sinf(a);
      tabHC[tid] = cosf(a);
    } else {
      int t2 = tid - HH * 32;
      int i = t2 >> 5;
      float w = -1.f + 2.f * (float)i / (float)(WW - 1);
      float a = w * theta;
      tabWS[t2] = sinf(a);
      tabWC[t2] = cosf(a);
    }
  } else if (tid < ntab + BB * HW_) {
    map[tid - ntab] = -1;
  }
}

// ------ gather + RoPE + LN1 + QKV via MFMA; 32 points/block (2 blocks/CU) ---
__global__ __launch_bounds__(256) void qkv_kernel(
    const float* __restrict__ pillar, const int* __restrict__ vidx,
    const float* __restrict__ tabHS, const float* __restrict__ tabHC,
    const float* __restrict__ tabWS, const float* __restrict__ tabWC,
    const float* __restrict__ qw, const float* __restrict__ kw,
    const float* __restrict__ vw,
    const float* __restrict__ qb, const float* __restrict__ kbias,
    const float* __restrict__ vb,
    const float* __restrict__ n1g, const float* __restrict__ n1b,
    float* __restrict__ g_out, unsigned short* __restrict__ Qb,
    unsigned short* __restrict__ Kb, unsigned short* __restrict__ Vt,
    int* __restrict__ map) {
  __shared__ unsigned short Aln[32][72];
  __shared__ unsigned short Wq[64][72], Wk[64][72], Wv[64][72];
  __shared__ unsigned int Vbo[64][20];
  int tid = threadIdx.x, wid = tid >> 6, lane = tid & 63;
  int l16 = lane & 15, lg = lane >> 4;
  int pt0 = blockIdx.x * 32;
  int b = pt0 >> 13, n0 = pt0 & (NN - 1);

  {
    int c = tid >> 2, k0 = (tid & 3) * 16;
#pragma unroll
    for (int mmm = 0; mmm < 3; mmm++) {
      const float* src = (mmm == 0 ? qw : mmm == 1 ? kw : vw) + c * 64 + k0;
      unsigned int pk[8];
#pragma unroll
      for (int j = 0; j < 8; j++) {
        float lo = src[2 * j], hi = src[2 * j + 1];
        asm("v_cvt_pk_bf16_f32 %0, %1, %2" : "=v"(pk[j]) : "v"(lo), "v"(hi));
      }
      unsigned short(*Wm)[72] = mmm == 0 ? Wq : mmm == 1 ? Wk : Wv;
      unsigned int* dst = (unsigned int*)&Wm[c][k0];
      *(uint4*)dst = make_uint4(pk[0], pk[1], pk[2], pk[3]);
      *(uint4*)(dst + 4) = make_uint4(pk[4], pk[5], pk[6], pk[7]);
    }
  }

  float n1g_l = n1g[lane], n1b_l = n1b[lane];
#pragma unroll 4
  for (int i = 0; i < 8; i++) {
    int p = wid * 8 + i;
    int pt = pt0 + p;
    float x = pillar[(size_t)pt * CC + lane];
    int pos = vidx[pt];
    int h = pos / WW, w = pos - h * WW;
    int j = lane & 31;
    float x1 = __shfl(x, j), x2 = __shfl(x, j + 32);
    float hs = tabHS[h * 32 + j], hc = tabHC[h * 32 + j];
    float ws = tabWS[w * 32 + j], wc = tabWC[w * 32 + j];
    float rope = (lane < 32) ? (x1 * hc * wc - x2 * hs * ws)
                             : (x1 * hs * ws + x2 * hc * wc);
    float gv = x + rope;
    g_out[(size_t)pt * CC + lane] = gv;
    float s = gv;
    for (int mm2 = 1; mm2 <= 32; mm2 <<= 1) s += __shfl_xor(s, mm2);
    float mean = s * (1.f / 64.f);
    float d = gv - mean;
    float vsum = d * d;
    for (int mm2 = 1; mm2 <= 32; mm2 <<= 1) vsum += __shfl_xor(vsum, mm2);
    float rstd = rsqrtf(vsum * (1.f / 64.f) + 1e-5f);
    float gn = d * rstd * n1g_l + n1b_l;
    Aln[p][lane] = f2bf(gn);
    if (lane == 0) map[b * HW_ + pos] = pt & (NN - 1);
  }
  __syncthreads();

#pragma unroll
  for (int j = 0; j < 6; j++) {
    int job = wid * 6 + j;
    int t = job / 12;
    int rem = job % 12;
    int mat = rem >> 2;
    int ct = rem & 3;
    bhalf8 aG0 = *(bhalf8*)&Aln[t * 16 + l16][lg * 8];
    bhalf8 aG1 = *(bhalf8*)&Aln[t * 16 + l16][32 + lg * 8];
    unsigned short(*Wm)[72] = mat == 0 ? Wq : mat == 1 ? Wk : Wv;
    bhalf8 bw0 = *(bhalf8*)&Wm[ct * 16 + l16][lg * 8];
    bhalf8 bw1 = *(bhalf8*)&Wm[ct * 16 + l16][32 + lg * 8];
    const float* bptr = mat == 0 ? qb : mat == 1 ? kbias : vb;
    float bias = bptr[ct * 16 + l16];
    f32x4 d = (f32x4){0.f, 0.f, 0.f, 0.f};
    d = __builtin_amdgcn_mfma_f32_16x16x32_bf16(aG0, bw0, d, 0, 0, 0);
    d = __builtin_amdgcn_mfma_f32_16x16x32_bf16(aG1, bw1, d, 0, 0, 0);
    if (mat == 0) {
#pragma unroll
      for (int r = 0; r < 4; r++) {
        size_t gi = (size_t)(pt0 + t * 16 + 4 * lg + r) * CC + ct * 16 + l16;
        Qb[gi] = f2bf((d[r] + bias) * LOG2E);  // log2-domain pre-scale
      }
    } else if (mat == 1) {
#pragma unroll
      for (int r = 0; r < 4; r++) {
        size_t gi = (size_t)(pt0 + t * 16 + 4 * lg + r) * CC + ct * 16 + l16;
        Kb[gi] = f2bf(d[r] + bias);
      }
    } else {
      float e0 = d[0] + bias, e1 = d[1] + bias;
      float e2 = d[2] + bias, e3 = d[3] + bias;
      unsigned int v0, v1;
      asm("v_cvt_pk_bf16_f32 %0, %1, %2" : "=v"(v0) : "v"(e0), "v"(e1));
      asm("v_cvt_pk_bf16_f32 %0, %1, %2" : "=v"(v1) : "v"(e2), "v"(e3));
      Vbo[ct * 16 + l16][t * 8 + 2 * lg + 0] = v0;
      Vbo[ct * 16 + l16][t * 8 + 2 * lg + 1] = v1;
    }
  }
  __syncthreads();
  {
    int c = tid >> 2, ch = tid & 3;
    uint4 w0 = *(uint4*)&Vbo[c][ch * 4];
    *(uint4*)(Vt + ((size_t)b * CC + c) * NN + n0 + ch * 8) = w0;
  }
}

// ------- flash attention: R12 body + L-via-ones-MFMA + v_max3 tree ---------
__global__ __attribute__((amdgpu_flat_work_group_size(512, 512),
                          amdgpu_waves_per_eu(4, 4))) void attn_kernel(
    const unsigned short* __restrict__ Qb, const unsigned short* __restrict__ Kb,
    const unsigned short* __restrict__ Vt,
    unsigned short* __restrict__ OPb, float* __restrict__ Mb,
    float* __restrict__ Lb) {
  __shared__ unsigned short Kt[2][64 * 64];
  __shared__ unsigned short Vl[2][64 * 64];
  __shared__ unsigned short Plds[8][32][72];
  int tidx = threadIdx.x;
  int wid = tidx >> 6, lane = tidx & 63;
  int l16 = lane & 15, lg = lane >> 4;
  int blk = blockIdx.x;
  int s = blk & (SPLIT - 1);
  int tb = blk >> 3;
  int b = tb >> 5;
  int tile = tb & 31;
  int q0 = tile * 256 + wid * 32;
  int kvbeg = s * KVPS;
  const unsigned short* Q = Qb + (size_t)b * NN * CC;
  const unsigned short* K = Kb + (size_t)b * NN * CC;
  const unsigned short* V = Vt + (size_t)b * CC * NN;

  bhalf8 bQ0 = *(const bhalf8*)(Q + (size_t)(q0 + l16) * CC + lg * 8);
  bhalf8 bQ1 = *(const bhalf8*)(Q + (size_t)(q0 + l16) * CC + 32 + lg * 8);
  bhalf8 bQ2 = *(const bhalf8*)(Q + (size_t)(q0 + 16 + l16) * CC + lg * 8);
  bhalf8 bQ3 = *(const bhalf8*)(Q + (size_t)(q0 + 16 + l16) * CC + 32 + lg * 8);

  int r8 = lane >> 3, chn = lane & 7;
  int sch = chn ^ r8;
  const unsigned short* Ksrc = K + (size_t)(8 * wid + r8) * CC + sch * 8;
  const unsigned short* Vsrc = V + (size_t)(8 * wid + r8) * NN + sch * 8;
  unsigned short* KtW = &Kt[0][0] + (8 * wid) * 64;
  unsigned short* VlW = &Vl[0][0] + (8 * wid) * 64;

  // ones B-fragment (bf16 1.0 = 0x3F80) for L row-sums on the MFMA pipe
  bhalf8 ones;
#pragma unroll
  for (int i = 0; i < 8; i++) ones[i] = (short)0x3F80;

  f32x4 acc0[4], acc1[4], accL0, accL1;
#pragma unroll
  for (int i = 0; i < 4; i++) {
    acc0[i] = (f32x4){0.f, 0.f, 0.f, 0.f};
    acc1[i] = (f32x4){0.f, 0.f, 0.f, 0.f};
  }
  accL0 = (f32x4){0.f, 0.f, 0.f, 0.f};
  accL1 = (f32x4){0.f, 0.f, 0.f, 0.f};
  float m = -1e30f;
  int sw8 = (l16 & 7) * 8;

  auto stage = [&](int bufi, int kv0) {
    gload16(Ksrc + (size_t)kv0 * CC, KtW + bufi * 4096);
    gload16(Vsrc + kv0, VlW + bufi * 4096);
  };

  auto body = [&](int buf, int kv0) {
    const unsigned short* Kb_ = &Kt[buf][0];
    const unsigned short* Vb_ = &Vl[buf][0];
    f32x4 St[4], Su[4];
    __builtin_amdgcn_s_setprio(1);
#pragma unroll
    for (int t = 0; t < 4; t++) {
      const unsigned short* kr = Kb_ + (16 * t + l16) * 64;
      bhalf8 aK0 = *(const bhalf8*)(kr + ((lg * 8) ^ sw8));
      bhalf8 aK1 = *(const bhalf8*)(kr + (((lg + 4) * 8) ^ sw8));
      f32x4 sa = (f32x4){0.f, 0.f, 0.f, 0.f};
      f32x4 sb = (f32x4){0.f, 0.f, 0.f, 0.f};
      sa = __builtin_amdgcn_mfma_f32_16x16x32_bf16(aK0, bQ0, sa, 0, 0, 0);
      sa = __builtin_amdgcn_mfma_f32_16x16x32_bf16(aK1, bQ1, sa, 0, 0, 0);
      sb = __builtin_amdgcn_mfma_f32_16x16x32_bf16(aK0, bQ2, sb, 0, 0, 0);
      sb = __builtin_amdgcn_mfma_f32_16x16x32_bf16(aK1, bQ3, sb, 0, 0, 0);
      St[t] = sa;
      Su[t] = sb;
    }
    __builtin_amdgcn_s_setprio(0);
    // max over both halves via v_max3-friendly triple chain (32 -> ~16 ops)
    float pm = fmaxf(fmaxf(St[0][0], St[0][1]), St[0][2]);
    pm = fmaxf(fmaxf(pm, St[0][3]), St[1][0]);
    pm = fmaxf(fmaxf(pm, St[1][1]), St[1][2]);
    pm = fmaxf(fmaxf(pm, St[1][3]), St[2][0]);
    pm = fmaxf(fmaxf(pm, St[2][1]), St[2][2]);
    pm = fmaxf(fmaxf(pm, St[2][3]), St[3][0]);
    pm = fmaxf(fmaxf(pm, St[3][1]), St[3][2]);
    pm = fmaxf(fmaxf(pm, St[3][3]), Su[0][0]);
    pm = fmaxf(fmaxf(pm, Su[0][1]), Su[0][2]);
    pm = fmaxf(fmaxf(pm, Su[0][3]), Su[1][0]);
    pm = fmaxf(fmaxf(pm, Su[1][1]), Su[1][2]);
    pm = fmaxf(fmaxf(pm, Su[1][3]), Su[2][0]);
    pm = fmaxf(fmaxf(pm, Su[2][1]), Su[2][2]);
    pm = fmaxf(fmaxf(pm, Su[2][3]), Su[3][0]);
    pm = fmaxf(fmaxf(pm, Su[3][1]), Su[3][2]);
    pm = fmaxf(pm, Su[3][3]);
    pm = fmaxf(pm, __shfl_xor(pm, 16));
    pm = fmaxf(pm, __shfl_xor(pm, 32));
    if (!__all(pm <= m + DEFER_THR)) {
      float mn = fmaxf(m, pm);
      float sc = EXP2(m - mn);
      m = mn;
      float scq[4];
#pragma unroll
      for (int r = 0; r < 4; r++) scq[r] = __shfl(sc, 4 * lg + r);
#pragma unroll
      for (int cg = 0; cg < 4; cg++)
#pragma unroll
        for (int r = 0; r < 4; r++) {
          acc0[cg][r] *= scq[r];
          acc1[cg][r] *= scq[r];
        }
#pragma unroll
      for (int r = 0; r < 4; r++) {
        accL0[r] *= scq[r];
        accL1[r] *= scq[r];
      }
    }
    // P = 2^(S' - m); no per-lane L adds (L comes from ones-MFMA below)
#pragma unroll
    for (int t = 0; t < 4; t++)
#pragma unroll
      for (int r = 0; r < 4; r++) {
        St[t][r] = EXP2(St[t][r] - m);
        Su[t][r] = EXP2(Su[t][r] - m);
      }
#pragma unroll
    for (int t = 0; t < 4; t++) {
      unsigned int pw0, pw1, pw2, pw3;
      float a0 = St[t][0], a1 = St[t][1], a2 = St[t][2], a3 = St[t][3];
      float b0 = Su[t][0], b1 = Su[t][1], b2 = Su[t][2], b3 = Su[t][3];
      asm("v_cvt_pk_bf16_f32 %0, %1, %2" : "=v"(pw0) : "v"(a0), "v"(a1));
      asm("v_cvt_pk_bf16_f32 %0, %1, %2" : "=v"(pw1) : "v"(a2), "v"(a3));
      asm("v_cvt_pk_bf16_f32 %0, %1, %2" : "=v"(pw2) : "v"(b0), "v"(b1));
      asm("v_cvt_pk_bf16_f32 %0, %1, %2" : "=v"(pw3) : "v"(b2), "v"(b3));
      *(uint2*)&Plds[wid][l16][16 * t + 4 * lg] = make_uint2(pw0, pw1);
      *(uint2*)&Plds[wid][16 + l16][16 * t + 4 * lg] = make_uint2(pw2, pw3);
    }
#pragma unroll
    for (int ch = 0; ch < 2; ch++) {
      bhalf8 aP0 = *(bhalf8*)&Plds[wid][l16][ch * 32 + lg * 8];
      bhalf8 aP1 = *(bhalf8*)&Plds[wid][16 + l16][ch * 32 + lg * 8];
      __builtin_amdgcn_s_setprio(1);
#pragma unroll
      for (int cg = 0; cg < 4; cg++) {
        bhalf8 bV = *(const bhalf8*)(Vb_ + (cg * 16 + l16) * 64 +
                                     (((4 * ch + lg) * 8) ^ sw8));
        acc0[cg] = __builtin_amdgcn_mfma_f32_16x16x32_bf16(aP0, bV, acc0[cg], 0, 0, 0);
        acc1[cg] = __builtin_amdgcn_mfma_f32_16x16x32_bf16(aP1, bV, acc1[cg], 0, 0, 0);
      }
      // L row-sums on the MFMA pipe (same bf16 P as the numerator)
      accL0 = __builtin_amdgcn_mfma_f32_16x16x32_bf16(aP0, ones, accL0, 0, 0, 0);
      accL1 = __builtin_amdgcn_mfma_f32_16x16x32_bf16(aP1, ones, accL1, 0, 0, 0);
      __builtin_amdgcn_s_setprio(0);
    }
  };

  stage(0, kvbeg);
  __syncthreads();
  const int nstep = KVPS / 64;  // 16, even
  for (int stp = 0; stp < nstep; stp += 2) {
    int kv0 = kvbeg + stp * 64;
    if (stp + 1 < nstep) stage(1, kv0 + 64);
    body(0, kv0);
    __syncthreads();
    if (stp + 2 < nstep) stage(0, kv0 + 128);
    body(1, kv0 + 64);
    __syncthreads();
  }
  size_t rowb = ((size_t)s * BB + b) * NN;
#pragma unroll
  for (int cg = 0; cg < 4; cg++)
#pragma unroll
    for (int r = 0; r < 4; r++) {
      OPb[(rowb + q0 + 4 * lg + r) * CC + cg * 16 + l16] = f2bf(acc0[cg][r]);
      OPb[(rowb + q0 + 16 + 4 * lg + r) * CC + cg * 16 + l16] = f2bf(acc1[cg][r]);
    }
  // L rows live at q = 4*lg + r (identical across the 16 cols); m is
  // wave-uniform. Write from col 0 lanes.
  if (l16 == 0) {
#pragma unroll
    for (int r = 0; r < 4; r++) {
      Mb[rowb + q0 + 4 * lg + r] = m;
      Lb[rowb + q0 + 4 * lg + r] = accL0[r];
      Mb[rowb + q0 + 16 + 4 * lg + r] = m;
      Lb[rowb + q0 + 16 + 4 * lg + r] = accL1[r];
    }
  }
}

// ---- combine + residual + LN2 + FFN; 32 points/block (2 blocks/CU) --------
__global__ __launch_bounds__(256) void ffn_kernel(
    const unsigned short* __restrict__ OPb, const float* __restrict__ Mb,
    const float* __restrict__ Lb, const float* __restrict__ g_in,
    const float* __restrict__ w1, const float* __restrict__ w2,
    const float* __restrict__ b1, const float* __restrict__ b2,
    const float* __restrict__ n2g, const float* __restrict__ n2b,
    float* __restrict__ upd) {
  __shared__ unsigned short Atile[32][72];
  __shared__ unsigned short Htile[32][72];
  __shared__ float aT[32][66];
  __shared__ unsigned short W1[64][72], W2[64][72];
  int tid = threadIdx.x, wid = tid >> 6, lane = tid & 63;
  int l16 = lane & 15, lg = lane >> 4;
  int pt0 = blockIdx.x * 32;

  {
    int c = tid >> 2, k0 = (tid & 3) * 16;
#pragma unroll
    for (int mmm = 0; mmm < 2; mmm++) {
      const float* src = (mmm == 0 ? w1 : w2) + c * 64 + k0;
      unsigned int pk[8];
#pragma unroll
      for (int j = 0; j < 8; j++) {
        float lo = src[2 * j], hi = src[2 * j + 1];
        asm("v_cvt_pk_bf16_f32 %0, %1, %2" : "=v"(pk[j]) : "v"(lo), "v"(hi));
      }
      unsigned short(*Wm)[72] = mmm == 0 ? W1 : W2;
      unsigned int* dst = (unsigned int*)&Wm[c][k0];
      *(uint4*)dst = make_uint4(pk[0], pk[1], pk[2], pk[3]);
      *(uint4*)(dst + 4) = make_uint4(pk[4], pk[5], pk[6], pk[7]);
    }
  }

  float n2g_l = n2g[lane], n2b_l = n2b[lane];
#pragma unroll 2
  for (int i = 0; i < 8; i++) {
    int p = wid * 8 + i;
    int pt = pt0 + p;
    float M = -1e30f;
    float mv[SPLIT];
#pragma unroll
    for (int s = 0; s < SPLIT; s++) {
      mv[s] = Mb[s * (BB * NN) + pt];
      M = fmaxf(M, mv[s]);
    }
    float accv = 0.f, Ls = 0.f;
#pragma unroll
    for (int s = 0; s < SPLIT; s++) {
      float w = EXP2(mv[s] - M);
      accv += w * bf2f(OPb[((size_t)s * (BB * NN) + pt) * CC + lane]);
      Ls += w * Lb[s * (BB * NN) + pt];
    }
    float a = accv / Ls + g_in[(size_t)pt * CC + lane];
    aT[p][lane] = a;
    float s2 = a;
    for (int mm2 = 1; mm2 <= 32; mm2 <<= 1) s2 += __shfl_xor(s2, mm2);
    float mean = s2 * (1.f / 64.f);
    float d = a - mean;
    float vsum = d * d;
    for (int mm2 = 1; mm2 <= 32; mm2 <<= 1) vsum += __shfl_xor(vsum, mm2);
    float rstd = rsqrtf(vsum * (1.f / 64.f) + 1e-5f);
    Atile[p][lane] = f2bf(d * rstd * n2g_l + n2b_l);
  }
  __syncthreads();

#pragma unroll
  for (int j = 0; j < 2; j++) {
    int job = wid * 2 + j;
    int t = job >> 2, ct = job & 3;
    bhalf8 aH0 = *(bhalf8*)&Atile[t * 16 + l16][lg * 8];
    bhalf8 aH1 = *(bhalf8*)&Atile[t * 16 + l16][32 + lg * 8];
    bhalf8 bw0 = *(bhalf8*)&W1[ct * 16 + l16][lg * 8];
    bhalf8 bw1 = *(bhalf8*)&W1[ct * 16 + l16][32 + lg * 8];
    float b1v = b1[ct * 16 + l16];
    f32x4 d1 = (f32x4){0.f, 0.f, 0.f, 0.f};
    d1 = __builtin_amdgcn_mfma_f32_16x16x32_bf16(aH0, bw0, d1, 0, 0, 0);
    d1 = __builtin_amdgcn_mfma_f32_16x16x32_bf16(aH1, bw1, d1, 0, 0, 0);
#pragma unroll
    for (int r = 0; r < 4; r++) {
      float h = d1[r] + b1v;
      h = 0.5f * h * (1.f + erff(h * 0.70710678118654752f));
      Htile[t * 16 + 4 * lg + r][ct * 16 + l16] = f2bf(h);
    }
  }
  __syncthreads();

#pragma unroll
  for (int j = 0; j < 2; j++) {
    int job = wid * 2 + j;
    int t = job >> 2, ct = job & 3;
    bhalf8 aF0 = *(bhalf8*)&Htile[t * 16 + l16][lg * 8];
    bhalf8 aF1 = *(bhalf8*)&Htile[t * 16 + l16][32 + lg * 8];
    bhalf8 bw0 = *(bhalf8*)&W2[ct * 16 + l16][lg * 8];
    bhalf8 bw1 = *(bhalf8*)&W2[ct * 16 + l16][32 + lg * 8];
    float b2v = b2[ct * 16 + l16];
    f32x4 d2 = (f32x4){0.f, 0.f, 0.f, 0.f};
    d2 = __builtin_amdgcn_mfma_f32_16x16x32_bf16(aF0, bw0, d2, 0, 0, 0);
    d2 = __builtin_amdgcn_mfma_f32_16x16x32_bf16(aF1, bw1, d2, 0, 0, 0);
#pragma unroll
    for (int r = 0; r < 4; r++) {
      int p = t * 16 + 4 * lg + r;
      upd[(size_t)(pt0 + p) * CC + ct * 16 + l16] = d2[r] + b2v + aT[p][ct * 16 + l16];
    }
  }
}

// ------ dense output write: 4 positions/thread, float4 stores --------------
__global__ __launch_bounds__(256) void out_kernel(
    const int* __restrict__ map, const float* __restrict__ upd,
    float* __restrict__ out) {
  int b = blockIdx.x / NB4;
  int p4 = (blockIdx.x % NB4) * 1024 + threadIdx.x * 4;
  if (p4 >= HW_) return;
  int r0 = map[b * HW_ + p4 + 0];
  int r1 = map[b * HW_ + p4 + 1];
  int r2 = map[b * HW_ + p4 + 2];
  int r3 = map[b * HW_ + p4 + 3];
  const float* base = upd + (size_t)b * NN * CC;
  float* o = out + (size_t)b * CC * HW_ + p4;
  float4 z = make_float4(0.f, 0.f, 0.f, 0.f);
#pragma unroll
  for (int cg = 0; cg < 16; cg++) {
    float4 v0 = (r0 >= 0) ? *(const float4*)(base + (size_t)r0 * CC + cg * 4) : z;
    float4 v1 = (r1 >= 0) ? *(const float4*)(base + (size_t)r1 * CC + cg * 4) : z;
    float4 v2 = (r2 >= 0) ? *(const float4*)(base + (size_t)r2 * CC + cg * 4) : z;
    float4 v3 = (r3 >= 0) ? *(const float4*)(base + (size_t)r3 * CC + cg * 4) : z;
    *(float4*)(o + (size_t)(cg * 4 + 0) * HW_) = make_float4(v0.x, v1.x, v2.x, v3.x);
    *(float4*)(o + (size_t)(cg * 4 + 1) * HW_) = make_float4(v0.y, v1.y, v2.y, v3.y);
    *(float4*)(o + (size_t)(cg * 4 + 2) * HW_) = make_float4(v0.z, v1.z, v2.z, v3.z);
    *(float4*)(o + (size_t)(cg * 4 + 3) * HW_) = make_float4(v0.w, v1.w, v2.w, v3.w);
  }
}

extern "C" void kernel_launch(void* const* d_in, const int* in_sizes, int n_in,
                              void* d_out, int out_size, void* d_ws, size_t ws_size,
                              hipStream_t stream) {
  const float* pillar = (const float*)d_in[0];
  const int* vidx = (const int*)d_in[1];
  const float* qw = (const float*)d_in[2];
  const float* qb = (const float*)d_in[3];
  const float* kw = (const float*)d_in[4];
  const float* kb = (const float*)d_in[5];
  const float* vw = (const float*)d_in[6];
  const float* vb = (const float*)d_in[7];
  const float* w1 = (const float*)d_in[8];
  const float* b1 = (const float*)d_in[9];
  const float* w2 = (const float*)d_in[10];
  const float* b2 = (const float*)d_in[11];
  const float* n1g = (const float*)d_in[12];
  const float* n1b = (const float*)d_in[13];
  const float* n2g = (const float*)d_in[14];
  const float* n2b = (const float*)d_in[15];
  float* out = (float*)d_out;

  char* ws = (char*)d_ws;
  size_t off = 0;
  auto take = [&](size_t bytes) -> char* {
    off = (off + 255) & ~(size_t)255;
    char* p = ws + off;
    off += bytes;
    return p;
  };
  float* tabHS = (float*)take((size_t)HH * 32 * 4);
  float* tabHC = (float*)take((size_t)HH * 32 * 4);
  float* tabWS = (float*)take((size_t)WW * 32 * 4);
  float* tabWC = (float*)take((size_t)WW * 32 * 4);
  float* gbuf = (float*)take((size_t)BB * NN * CC * 4);
  float* updb = (float*)take((size_t)BB * NN * CC * 4);
  unsigned short* Qb = (unsigned short*)take((size_t)BB * NN * CC * 2);
  unsigned short* Kb = (unsigned short*)take((size_t)BB * NN * CC * 2);
  unsigned short* Vt = (unsigned short*)take((size_t)BB * CC * NN * 2);
  unsigned short* OPb = (unsigned short*)take((size_t)SPLIT * BB * NN * CC * 2);
  float* Mbuf = (float*)take((size_t)SPLIT * BB * NN * 4);
  float* Lbuf = (float*)take((size_t)SPLIT * BB * NN * 4);
  int* map = (int*)take((size_t)BB * HW_ * 4);

  int preptot = (HH + WW) * 32 + BB * HW_;
  prep_kernel<<<(preptot + 255) / 256, 256, 0, stream>>>(
      tabHS, tabHC, tabWS, tabWC, map);
  qkv_kernel<<<BB * NN / 32, 256, 0, stream>>>(
      pillar, vidx, tabHS, tabHC, tabWS, tabWC, qw, kw, vw, qb, kb, vb,
      n1g, n1b, gbuf, Qb, Kb, Vt, map);
  attn_kernel<<<BB * (NN / 256) * SPLIT, 512, 0, stream>>>(Qb, Kb, Vt, OPb, Mbuf, Lbuf);
  ffn_kernel<<<BB * NN / 32, 256, 0, stream>>>(OPb, Mbuf, Lbuf, gbuf, w1, w2,
                                               b1, b2, n2g, n2b, updb);
  out_kernel<<<BB * NB4, 256, 0, stream>>>(map, updb, out);
}